// Round 13
// baseline (200.194 us; speedup 1.0000x reference)
//
#include <hip/hip_runtime.h>
#include <math.h>

#define N_NODES 100000
#define N_EDGES 3200000
#define IN_DIM  128
#define OUT_DIM 64

#define BSHIFT   7
#define BNODES   128                                   // nodes per bucket
#define NBUCKETS ((N_NODES + BNODES - 1) / BNODES)     // 782
#define NBINBLK  1024
#define CHUNK    (N_EDGES / NBINBLK)                   // 3125 (exact)
#define SEGCAP   6144                                  // max edges/bucket
#define MTILES   (N_NODES / 16)                        // 6250 (exact)

typedef _Float16 half8 __attribute__((ext_vector_type(8)));
typedef float    f32x4 __attribute__((ext_vector_type(4)));

// XCD-aware swizzle (verified round 11): 128 consecutive logical blocks per
// XCD -> bucket-major ebuf segments write-combine in one L2.
__device__ __forceinline__ int xcd_swz(int i) {
    return (i & 7) * (NBINBLK / 8) + (i >> 3);   // bijective: 1024 = 8*128
}

// ---------------------------------------------------------------------------
// Kernel 1 (MFMA): base(fp16) = feature @ W_lin ; u1 = tanh(base) as fp16.
// (verified round 9; base narrowed to fp16 round 13)
// ---------------------------------------------------------------------------
__global__ __launch_bounds__(256) void gemm_base_tanh(
    const float* __restrict__ feature,
    const float* __restrict__ Wlin,     // [128][64] row-major fp32
    _Float16* __restrict__ baseh,
    _Float16* __restrict__ u1h)
{
    int lane = threadIdx.x & 63;
    int wid  = (blockIdx.x * 256 + threadIdx.x) >> 6;
    if (wid >= MTILES) return;

    int mrow = lane & 15;       // A row / B col / C col
    int kb   = lane >> 4;       // k-block 0..3
    int k0   = kb * 8;

    half8 b[4][4];
#pragma unroll
    for (int s = 0; s < 4; ++s)
#pragma unroll
        for (int n = 0; n < 4; ++n)
#pragma unroll
            for (int j = 0; j < 8; ++j)
                b[s][n][j] = (_Float16)Wlin[(s * 32 + k0 + j) * OUT_DIM + n * 16 + mrow];

    int row = wid * 16 + mrow;
    const float4* fr = reinterpret_cast<const float4*>(feature + (size_t)row * IN_DIM);
    half8 a[4];
#pragma unroll
    for (int s = 0; s < 4; ++s) {
        float4 lo = fr[(s * 32 + k0) >> 2];
        float4 hi = fr[((s * 32 + k0) >> 2) + 1];
        a[s][0] = (_Float16)lo.x; a[s][1] = (_Float16)lo.y;
        a[s][2] = (_Float16)lo.z; a[s][3] = (_Float16)lo.w;
        a[s][4] = (_Float16)hi.x; a[s][5] = (_Float16)hi.y;
        a[s][6] = (_Float16)hi.z; a[s][7] = (_Float16)hi.w;
    }

    f32x4 acc[4];
#pragma unroll
    for (int n = 0; n < 4; ++n) acc[n] = (f32x4)0.f;

#pragma unroll
    for (int s = 0; s < 4; ++s)
#pragma unroll
        for (int n = 0; n < 4; ++n)
            acc[n] = __builtin_amdgcn_mfma_f32_16x16x32_f16(a[s], b[s][n], acc[n], 0, 0, 0);

#pragma unroll
    for (int n = 0; n < 4; ++n)
#pragma unroll
        for (int j = 0; j < 4; ++j) {
            int r = wid * 16 + kb * 4 + j;
            int c = n * 16 + mrow;
            float v = acc[n][j];
            baseh[(size_t)r * OUT_DIM + c] = (_Float16)v;
            u1h[(size_t)r * OUT_DIM + c]  = (_Float16)tanhf(v);
        }
}

// ---------------------------------------------------------------------------
// bin_hist: per-block LDS histogram of dst>>7; writes H[k][b] AND
// accumulates global bucket totals (int atomics, bit-exact).
// ---------------------------------------------------------------------------
__global__ __launch_bounds__(256) void bin_hist(
    const int* __restrict__ dst, int* __restrict__ H, int* __restrict__ tot)
{
    __shared__ int h[NBUCKETS];
    for (int k = threadIdx.x; k < NBUCKETS; k += 256) h[k] = 0;
    __syncthreads();

    int b = xcd_swz(blockIdx.x);
    int beg = b * CHUNK, end = beg + CHUNK;
    for (int i = beg + threadIdx.x; i < end; i += 256)
        atomicAdd(&h[dst[i] >> BSHIFT], 1);
    __syncthreads();

    for (int k = threadIdx.x; k < NBUCKETS; k += 256) {
        int v = h[k];
        H[(size_t)k * NBINBLK + b] = v;
        if (v) atomicAdd(&tot[k], v);
    }
}

// ---------------------------------------------------------------------------
// scan_tot: exclusive scan of bucket totals -> bucket bases; sets H[T].
// ---------------------------------------------------------------------------
__global__ __launch_bounds__(1024) void scan_tot(
    int* __restrict__ Btot, int* __restrict__ H)
{
    __shared__ int s[1024];
    int t = threadIdx.x;
    int v = (t < NBUCKETS) ? Btot[t] : 0;
    s[t] = v;
    __syncthreads();
#pragma unroll
    for (int off = 1; off < 1024; off <<= 1) {
        int x = (t >= off) ? s[t - off] : 0;
        __syncthreads();
        s[t] += x;
        __syncthreads();
    }
    if (t < NBUCKETS) Btot[t] = s[t] - v;       // exclusive bucket base
    if (t == 0) H[(size_t)NBUCKETS * NBINBLK] = N_EDGES;
}

// ---------------------------------------------------------------------------
// scan_local: per-bucket exclusive scan of H row + add bucket base
// (global offsets written directly; add_base kernel folded away).
// ---------------------------------------------------------------------------
__global__ __launch_bounds__(NBINBLK) void scan_local(
    int* __restrict__ H, const int* __restrict__ Btot)
{
    __shared__ int s[NBINBLK];
    int k = blockIdx.x, t = threadIdx.x;
    int v = H[(size_t)k * NBINBLK + t];
    s[t] = v;
    __syncthreads();
#pragma unroll
    for (int off = 1; off < NBINBLK; off <<= 1) {
        int x = (t >= off) ? s[t - off] : 0;
        __syncthreads();
        s[t] += x;
        __syncthreads();
    }
    H[(size_t)k * NBINBLK + t] = (s[t] - v) + Btot[k];
}

// ---------------------------------------------------------------------------
// bin_scatter (verified with XCD swizzle)
// ---------------------------------------------------------------------------
__global__ __launch_bounds__(256) void bin_scatter(
    const int* __restrict__ src,
    const int* __restrict__ dst,
    const int* __restrict__ H,
    int* __restrict__ ebuf)
{
    __shared__ int cur[NBUCKETS];
    int b = xcd_swz(blockIdx.x);
    for (int k = threadIdx.x; k < NBUCKETS; k += 256)
        cur[k] = H[(size_t)k * NBINBLK + b];
    __syncthreads();

    int beg = b * CHUNK, end = beg + CHUNK;
    for (int i = beg + threadIdx.x; i < end; i += 256) {
        int d = dst[i];
        int k = d >> BSHIFT;
        int p = atomicAdd(&cur[k], 1);
        // pack: src (17 bits) | dlocal (7 bits) << 17
        ebuf[p] = src[i] | ((d & (BNODES - 1)) << 17);
    }
}

// ---------------------------------------------------------------------------
// bucket_sort (verified)
// ---------------------------------------------------------------------------
__global__ __launch_bounds__(256) void bucket_sort(
    const int* __restrict__ H,
    int* __restrict__ ebuf,
    int* __restrict__ node_off)
{
    __shared__ int seg[SEGCAP];
    __shared__ int cnt[BNODES];
    __shared__ int off[BNODES];
    int k = blockIdx.x;
    int beg = H[(size_t)k * NBINBLK];
    int end = H[(size_t)(k + 1) * NBINBLK];
    int n = end - beg;

    for (int j = threadIdx.x; j < BNODES; j += 256) cnt[j] = 0;
    __syncthreads();

    for (int i = threadIdx.x; i < n; i += 256) {
        int v = ebuf[beg + i];
        seg[i] = v;
        atomicAdd(&cnt[v >> 17], 1);
    }
    __syncthreads();

    if (threadIdx.x == 0) {
        int node0 = k * BNODES;
        int nvalid = N_NODES - node0; if (nvalid > BNODES) nvalid = BNODES;
        int excl = 0;
        for (int j = 0; j < nvalid; ++j) {
            off[j] = excl;
            node_off[node0 + j] = beg + excl;
            excl += cnt[j];
        }
        if (k == NBUCKETS - 1) node_off[N_NODES] = end;
    }
    __syncthreads();

    for (int i = threadIdx.x; i < n; i += 256) {
        int v = seg[i];
        int p = atomicAdd(&off[v >> 17], 1);
        ebuf[beg + p] = v & 0x1FFFF;
    }
}

// ---------------------------------------------------------------------------
// Gather: one wave per node over fp16 u1 rows.  Round 13: each q-group
// (8 lanes) takes a CONTIGUOUS eighth of the node's edge list and runs its
// own 4-deep unroll -- mean-degree-32 node = exactly one 4-deep iteration
// per group, no long serial tail (was 1 main + ~4 ILP-1 tail iters).
// ---------------------------------------------------------------------------
__global__ __launch_bounds__(256) void node_gather(
    const int* __restrict__ node_off,
    const int* __restrict__ csr,
    const half8* __restrict__ u1v,      // [N_NODES][8]
    float* __restrict__ m)
{
    int wid = (blockIdx.x * 256 + threadIdx.x) >> 6;
    if (wid >= N_NODES) return;
    int lane = threadIdx.x & 63;
    int q = lane >> 3, c = lane & 7;

    int beg = node_off[wid];
    int end = node_off[wid + 1];
    int cnt = end - beg;
    int per = (cnt + 7) >> 3;           // edges per q-group (contiguous)
    int gb  = beg + q * per;
    int ge  = gb + per; if (ge > end) ge = end;

    float acc[8];
#pragma unroll
    for (int i = 0; i < 8; ++i) acc[i] = 0.f;

    int e = gb;
    for (; e + 4 <= ge; e += 4) {
        int s0 = csr[e];
        int s1 = csr[e + 1];
        int s2 = csr[e + 2];
        int s3 = csr[e + 3];
        half8 a = u1v[(size_t)s0 * 8 + c];
        half8 b = u1v[(size_t)s1 * 8 + c];
        half8 g = u1v[(size_t)s2 * 8 + c];
        half8 d = u1v[(size_t)s3 * 8 + c];
#pragma unroll
        for (int i = 0; i < 8; ++i)
            acc[i] += ((float)a[i] + (float)b[i]) + ((float)g[i] + (float)d[i]);
    }
    for (; e < ge; ++e) {
        half8 a = u1v[(size_t)csr[e] * 8 + c];
#pragma unroll
        for (int i = 0; i < 8; ++i) acc[i] += (float)a[i];
    }

    // reduce across the 8 q-groups (lane bits 3,4,5)
#pragma unroll
    for (int i = 0; i < 8; ++i) {
        acc[i] += __shfl_xor(acc[i], 8);
        acc[i] += __shfl_xor(acc[i], 16);
        acc[i] += __shfl_xor(acc[i], 32);
    }

    if (q == 0) {
        float4* mr = reinterpret_cast<float4*>(m + (size_t)wid * OUT_DIM + c * 8);
        mr[0] = make_float4(acc[0], acc[1], acc[2], acc[3]);
        mr[1] = make_float4(acc[4], acc[5], acc[6], acc[7]);
    }
}

// ---------------------------------------------------------------------------
// Kernel 3 (MFMA): out = tanh(base + relu(m @ W_d1) @ W_d2)
// (verified round 12; base read as fp16 round 13)
// ---------------------------------------------------------------------------
__global__ __launch_bounds__(256) void dense_tanh(
    const float* __restrict__ m,
    const float* __restrict__ W1,       // [64][64]
    const float* __restrict__ W2,       // [64][64]
    const _Float16* __restrict__ baseh,
    float* __restrict__ out)
{
    __shared__ _Float16 tl[4][16][72];  // 9 KB: per-wave transpose tile
    int lane = threadIdx.x & 63;
    int w    = threadIdx.x >> 6;        // wave in block
    int wid  = (blockIdx.x * 256 + threadIdx.x) >> 6;
    if (wid >= MTILES) return;

    int mrow = lane & 15;
    int kb   = lane >> 4;
    int k0   = kb * 8;

    half8 b1[2][4], b2[2][4];
#pragma unroll
    for (int s = 0; s < 2; ++s)
#pragma unroll
        for (int n = 0; n < 4; ++n)
#pragma unroll
            for (int j = 0; j < 8; ++j) {
                b1[s][n][j] = (_Float16)W1[(s * 32 + k0 + j) * 64 + n * 16 + mrow];
                b2[s][n][j] = (_Float16)W2[(s * 32 + k0 + j) * 64 + n * 16 + mrow];
            }

    int row = wid * 16 + mrow;
    const float4* mr = reinterpret_cast<const float4*>(m + (size_t)row * 64);
    half8 a[2];
#pragma unroll
    for (int s = 0; s < 2; ++s) {
        float4 lo = mr[(s * 32 + k0) >> 2];
        float4 hi = mr[((s * 32 + k0) >> 2) + 1];
        a[s][0] = (_Float16)lo.x; a[s][1] = (_Float16)lo.y;
        a[s][2] = (_Float16)lo.z; a[s][3] = (_Float16)lo.w;
        a[s][4] = (_Float16)hi.x; a[s][5] = (_Float16)hi.y;
        a[s][6] = (_Float16)hi.z; a[s][7] = (_Float16)hi.w;
    }

    f32x4 acc1[4];
#pragma unroll
    for (int n = 0; n < 4; ++n) acc1[n] = (f32x4)0.f;
#pragma unroll
    for (int s = 0; s < 2; ++s)
#pragma unroll
        for (int n = 0; n < 4; ++n)
            acc1[n] = __builtin_amdgcn_mfma_f32_16x16x32_f16(a[s], b1[s][n], acc1[n], 0, 0, 0);

#pragma unroll
    for (int n = 0; n < 4; ++n)
#pragma unroll
        for (int j = 0; j < 4; ++j)
            tl[w][kb * 4 + j][n * 16 + mrow] = (_Float16)fmaxf(acc1[n][j], 0.f);

    half8 a2[2];
#pragma unroll
    for (int s = 0; s < 2; ++s)
        a2[s] = *reinterpret_cast<const half8*>(&tl[w][mrow][s * 32 + k0]);

    f32x4 acc2[4];
#pragma unroll
    for (int n = 0; n < 4; ++n) acc2[n] = (f32x4)0.f;
#pragma unroll
    for (int s = 0; s < 2; ++s)
#pragma unroll
        for (int n = 0; n < 4; ++n)
            acc2[n] = __builtin_amdgcn_mfma_f32_16x16x32_f16(a2[s], b2[s][n], acc2[n], 0, 0, 0);

#pragma unroll
    for (int n = 0; n < 4; ++n)
#pragma unroll
        for (int j = 0; j < 4; ++j) {
            int r = wid * 16 + kb * 4 + j;
            int c = n * 16 + mrow;
            float b0 = (float)baseh[(size_t)r * 64 + c];
            out[(size_t)r * 64 + c] = tanhf(b0 + acc2[n][j]);
        }
}

// ---------------------------------------------------------------------------
extern "C" void kernel_launch(void* const* d_in, const int* in_sizes, int n_in,
                              void* d_out, int out_size, void* d_ws, size_t ws_size,
                              hipStream_t stream)
{
    const float* feature = (const float*)d_in[0];
    const int*   src     = (const int*)d_in[1];
    const int*   dst     = (const int*)d_in[2];
    const float* W_lin   = (const float*)d_in[3];
    const float* W_d1    = (const float*)d_in[4];
    const float* W_d2    = (const float*)d_in[5];
    float* out = (float*)d_out;

    const size_t NODE_F = (size_t)N_NODES * OUT_DIM;   // 6.4M elems

    _Float16* baseh    = (_Float16*)d_ws;                       // 12.8 MB
    _Float16* u1h      = baseh + NODE_F;                        // 12.8 MB
    float*    m        = (float*)(u1h + NODE_F);                // 25.6 MB
    int*      H        = (int*)(m + NODE_F);                    // 3.2 MB (+1)
    int*      tot      = H + ((size_t)NBUCKETS * NBINBLK + 4);  // NBUCKETS
    int*      node_off = tot + (NBUCKETS + 4);                  // N_NODES+1
    int*      ebuf     = node_off + (N_NODES + 4);              // 12.8 MB

    hipMemsetAsync(tot, 0, NBUCKETS * sizeof(int), stream);

    // iter 1 collapses: u0 == 0 -> m == 0 -> h == 0 -> u1 = tanh(feature@W_lin)
    int gemm_blocks = (MTILES + 3) / 4;                // 4 waves/block
    gemm_base_tanh<<<gemm_blocks, 256, 0, stream>>>(feature, W_lin, baseh, u1h);

    bin_hist  <<<NBINBLK, 256, 0, stream>>>(dst, H, tot);
    scan_tot  <<<1, 1024, 0, stream>>>(tot, H);
    scan_local<<<NBUCKETS, NBINBLK, 0, stream>>>(H, tot);
    bin_scatter<<<NBINBLK, 256, 0, stream>>>(src, dst, H, ebuf);
    bucket_sort<<<NBUCKETS, 256, 0, stream>>>(H, ebuf, node_off);

    int gather_blocks = (int)(((size_t)N_NODES * 64 + 255) / 256);   // 25000
    node_gather<<<gather_blocks, 256, 0, stream>>>(
        node_off, ebuf, (const half8*)u1h, m);

    dense_tanh<<<gemm_blocks, 256, 0, stream>>>(m, W_d1, W_d2, baseh, out);
}

// Round 14
// 170.171 us; speedup vs baseline: 1.1764x; 1.1764x over previous
//
#include <hip/hip_runtime.h>
#include <math.h>

#define N_NODES 100000
#define N_EDGES 3200000
#define IN_DIM  128
#define OUT_DIM 64

#define BSHIFT   7
#define BNODES   128                                   // nodes per bucket
#define NBUCKETS ((N_NODES + BNODES - 1) / BNODES)     // 782
#define NBINBLK  1024
#define CHUNK    (N_EDGES / NBINBLK)                   // 3125 (exact)
#define SEGCAP   6144                                  // max edges/bucket
#define MTILES   (N_NODES / 16)                        // 6250 (exact)

typedef _Float16 half8 __attribute__((ext_vector_type(8)));
typedef float    f32x4 __attribute__((ext_vector_type(4)));

// XCD-aware swizzle (verified round 11): 128 consecutive logical blocks per
// XCD -> bucket-major ebuf segments write-combine in one L2.
__device__ __forceinline__ int xcd_swz(int i) {
    return (i & 7) * (NBINBLK / 8) + (i >> 3);   // bijective: 1024 = 8*128
}

// ---------------------------------------------------------------------------
// Kernel 1 (MFMA): base = feature @ W_lin ; u1 = tanh(base) as fp16.
// (verified rounds 9-12; base kept fp32 -- round-13 fp16 narrowing reverted)
// ---------------------------------------------------------------------------
__global__ __launch_bounds__(256) void gemm_base_tanh(
    const float* __restrict__ feature,
    const float* __restrict__ Wlin,     // [128][64] row-major fp32
    float* __restrict__ base,
    _Float16* __restrict__ u1h)
{
    int lane = threadIdx.x & 63;
    int wid  = (blockIdx.x * 256 + threadIdx.x) >> 6;
    if (wid >= MTILES) return;

    int mrow = lane & 15;       // A row / B col / C col
    int kb   = lane >> 4;       // k-block 0..3
    int k0   = kb * 8;

    half8 b[4][4];
#pragma unroll
    for (int s = 0; s < 4; ++s)
#pragma unroll
        for (int n = 0; n < 4; ++n)
#pragma unroll
            for (int j = 0; j < 8; ++j)
                b[s][n][j] = (_Float16)Wlin[(s * 32 + k0 + j) * OUT_DIM + n * 16 + mrow];

    int row = wid * 16 + mrow;
    const float4* fr = reinterpret_cast<const float4*>(feature + (size_t)row * IN_DIM);
    half8 a[4];
#pragma unroll
    for (int s = 0; s < 4; ++s) {
        float4 lo = fr[(s * 32 + k0) >> 2];
        float4 hi = fr[((s * 32 + k0) >> 2) + 1];
        a[s][0] = (_Float16)lo.x; a[s][1] = (_Float16)lo.y;
        a[s][2] = (_Float16)lo.z; a[s][3] = (_Float16)lo.w;
        a[s][4] = (_Float16)hi.x; a[s][5] = (_Float16)hi.y;
        a[s][6] = (_Float16)hi.z; a[s][7] = (_Float16)hi.w;
    }

    f32x4 acc[4];
#pragma unroll
    for (int n = 0; n < 4; ++n) acc[n] = (f32x4)0.f;

#pragma unroll
    for (int s = 0; s < 4; ++s)
#pragma unroll
        for (int n = 0; n < 4; ++n)
            acc[n] = __builtin_amdgcn_mfma_f32_16x16x32_f16(a[s], b[s][n], acc[n], 0, 0, 0);

#pragma unroll
    for (int n = 0; n < 4; ++n)
#pragma unroll
        for (int j = 0; j < 4; ++j) {
            int r = wid * 16 + kb * 4 + j;
            int c = n * 16 + mrow;
            float v = acc[n][j];
            base[(size_t)r * OUT_DIM + c] = v;
            u1h[(size_t)r * OUT_DIM + c] = (_Float16)tanhf(v);
        }
}

// ---------------------------------------------------------------------------
// Binning phase 1: per-block LDS histogram of dst>>7.  (verified round 12)
// ---------------------------------------------------------------------------
__global__ __launch_bounds__(256) void bin_hist(
    const int* __restrict__ dst, int* __restrict__ H)
{
    __shared__ int h[NBUCKETS];
    for (int k = threadIdx.x; k < NBUCKETS; k += 256) h[k] = 0;
    __syncthreads();

    int b = xcd_swz(blockIdx.x);
    int beg = b * CHUNK, end = beg + CHUNK;
    for (int i = beg + threadIdx.x; i < end; i += 256)
        atomicAdd(&h[dst[i] >> BSHIFT], 1);
    __syncthreads();

    for (int k = threadIdx.x; k < NBUCKETS; k += 256)
        H[(size_t)k * NBINBLK + b] = h[k];
}

// ---------------------------------------------------------------------------
// Hierarchical scan of H (bucket-major), bit-exact.  (verified round 12)
// ---------------------------------------------------------------------------
__global__ __launch_bounds__(NBINBLK) void scan_local(
    int* __restrict__ H, int* __restrict__ Btot)
{
    __shared__ int s[NBINBLK];
    int k = blockIdx.x, t = threadIdx.x;
    int v = H[(size_t)k * NBINBLK + t];
    s[t] = v;
    __syncthreads();
#pragma unroll
    for (int off = 1; off < NBINBLK; off <<= 1) {
        int x = (t >= off) ? s[t - off] : 0;
        __syncthreads();
        s[t] += x;
        __syncthreads();
    }
    H[(size_t)k * NBINBLK + t] = s[t] - v;      // exclusive
    if (t == NBINBLK - 1) Btot[k] = s[t];       // inclusive total
}

__global__ __launch_bounds__(1024) void scan_tot(int* __restrict__ Btot)
{
    __shared__ int s[1024];
    int t = threadIdx.x;
    int v = (t < NBUCKETS) ? Btot[t] : 0;
    s[t] = v;
    __syncthreads();
#pragma unroll
    for (int off = 1; off < 1024; off <<= 1) {
        int x = (t >= off) ? s[t - off] : 0;
        __syncthreads();
        s[t] += x;
        __syncthreads();
    }
    if (t < NBUCKETS) Btot[t] = s[t] - v;       // exclusive bucket base
}

__global__ __launch_bounds__(NBINBLK) void add_base(
    int* __restrict__ H, const int* __restrict__ Btot)
{
    int k = blockIdx.x, t = threadIdx.x;
    H[(size_t)k * NBINBLK + t] += Btot[k];
    if (k == 0 && t == 0) H[(size_t)NBUCKETS * NBINBLK] = N_EDGES;
}

// ---------------------------------------------------------------------------
// bin_scatter (verified with XCD swizzle, round 11)
// ---------------------------------------------------------------------------
__global__ __launch_bounds__(256) void bin_scatter(
    const int* __restrict__ src,
    const int* __restrict__ dst,
    const int* __restrict__ H,
    int* __restrict__ ebuf)
{
    __shared__ int cur[NBUCKETS];
    int b = xcd_swz(blockIdx.x);
    for (int k = threadIdx.x; k < NBUCKETS; k += 256)
        cur[k] = H[(size_t)k * NBINBLK + b];
    __syncthreads();

    int beg = b * CHUNK, end = beg + CHUNK;
    for (int i = beg + threadIdx.x; i < end; i += 256) {
        int d = dst[i];
        int k = d >> BSHIFT;
        int p = atomicAdd(&cur[k], 1);
        // pack: src (17 bits) | dlocal (7 bits) << 17
        ebuf[p] = src[i] | ((d & (BNODES - 1)) << 17);
    }
}

// ---------------------------------------------------------------------------
// bucket_sort (verified)
// ---------------------------------------------------------------------------
__global__ __launch_bounds__(256) void bucket_sort(
    const int* __restrict__ H,
    int* __restrict__ ebuf,
    int* __restrict__ node_off)
{
    __shared__ int seg[SEGCAP];
    __shared__ int cnt[BNODES];
    __shared__ int off[BNODES];
    int k = blockIdx.x;
    int beg = H[(size_t)k * NBINBLK];
    int end = H[(size_t)(k + 1) * NBINBLK];
    int n = end - beg;

    for (int j = threadIdx.x; j < BNODES; j += 256) cnt[j] = 0;
    __syncthreads();

    for (int i = threadIdx.x; i < n; i += 256) {
        int v = ebuf[beg + i];
        seg[i] = v;
        atomicAdd(&cnt[v >> 17], 1);
    }
    __syncthreads();

    if (threadIdx.x == 0) {
        int node0 = k * BNODES;
        int nvalid = N_NODES - node0; if (nvalid > BNODES) nvalid = BNODES;
        int excl = 0;
        for (int j = 0; j < nvalid; ++j) {
            off[j] = excl;
            node_off[node0 + j] = beg + excl;
            excl += cnt[j];
        }
        if (k == NBUCKETS - 1) node_off[N_NODES] = end;
    }
    __syncthreads();

    for (int i = threadIdx.x; i < n; i += 256) {
        int v = seg[i];
        int p = atomicAdd(&off[v >> 17], 1);
        ebuf[beg + p] = v & 0x1FFFF;
    }
}

// ---------------------------------------------------------------------------
// Gather: one wave per node over fp16 u1 rows.  Contiguous per-q-group
// chunking (same-kernel A/B r12->r13: 56.8 -> 55.7 us, kept): each q-group
// (8 lanes) takes a contiguous eighth of the node's edge list; deg~32 node
// = one 4-deep iteration per group, no long ILP-1 tail.
// ---------------------------------------------------------------------------
__global__ __launch_bounds__(256) void node_gather(
    const int* __restrict__ node_off,
    const int* __restrict__ csr,
    const half8* __restrict__ u1v,      // [N_NODES][8]
    float* __restrict__ m)
{
    int wid = (blockIdx.x * 256 + threadIdx.x) >> 6;
    if (wid >= N_NODES) return;
    int lane = threadIdx.x & 63;
    int q = lane >> 3, c = lane & 7;

    int beg = node_off[wid];
    int end = node_off[wid + 1];
    int cnt = end - beg;
    int per = (cnt + 7) >> 3;           // edges per q-group (contiguous)
    int gb  = beg + q * per;
    int ge  = gb + per; if (ge > end) ge = end;

    float acc[8];
#pragma unroll
    for (int i = 0; i < 8; ++i) acc[i] = 0.f;

    int e = gb;
    for (; e + 4 <= ge; e += 4) {
        int s0 = csr[e];
        int s1 = csr[e + 1];
        int s2 = csr[e + 2];
        int s3 = csr[e + 3];
        half8 a = u1v[(size_t)s0 * 8 + c];
        half8 b = u1v[(size_t)s1 * 8 + c];
        half8 g = u1v[(size_t)s2 * 8 + c];
        half8 d = u1v[(size_t)s3 * 8 + c];
#pragma unroll
        for (int i = 0; i < 8; ++i)
            acc[i] += ((float)a[i] + (float)b[i]) + ((float)g[i] + (float)d[i]);
    }
    for (; e < ge; ++e) {
        half8 a = u1v[(size_t)csr[e] * 8 + c];
#pragma unroll
        for (int i = 0; i < 8; ++i) acc[i] += (float)a[i];
    }

    // reduce across the 8 q-groups (lane bits 3,4,5)
#pragma unroll
    for (int i = 0; i < 8; ++i) {
        acc[i] += __shfl_xor(acc[i], 8);
        acc[i] += __shfl_xor(acc[i], 16);
        acc[i] += __shfl_xor(acc[i], 32);
    }

    if (q == 0) {
        float4* mr = reinterpret_cast<float4*>(m + (size_t)wid * OUT_DIM + c * 8);
        mr[0] = make_float4(acc[0], acc[1], acc[2], acc[3]);
        mr[1] = make_float4(acc[4], acc[5], acc[6], acc[7]);
    }
}

// ---------------------------------------------------------------------------
// Kernel 3 (MFMA): out = tanh(base + relu(m @ W_d1) @ W_d2)
// (verified round 12; base kept fp32)
// ---------------------------------------------------------------------------
__global__ __launch_bounds__(256) void dense_tanh(
    const float* __restrict__ m,
    const float* __restrict__ W1,       // [64][64]
    const float* __restrict__ W2,       // [64][64]
    const float* __restrict__ base,
    float* __restrict__ out)
{
    __shared__ _Float16 tl[4][16][72];  // 9 KB: per-wave transpose tile
    int lane = threadIdx.x & 63;
    int w    = threadIdx.x >> 6;        // wave in block
    int wid  = (blockIdx.x * 256 + threadIdx.x) >> 6;
    if (wid >= MTILES) return;

    int mrow = lane & 15;
    int kb   = lane >> 4;
    int k0   = kb * 8;

    half8 b1[2][4], b2[2][4];
#pragma unroll
    for (int s = 0; s < 2; ++s)
#pragma unroll
        for (int n = 0; n < 4; ++n)
#pragma unroll
            for (int j = 0; j < 8; ++j) {
                b1[s][n][j] = (_Float16)W1[(s * 32 + k0 + j) * 64 + n * 16 + mrow];
                b2[s][n][j] = (_Float16)W2[(s * 32 + k0 + j) * 64 + n * 16 + mrow];
            }

    int row = wid * 16 + mrow;
    const float4* mr = reinterpret_cast<const float4*>(m + (size_t)row * 64);
    half8 a[2];
#pragma unroll
    for (int s = 0; s < 2; ++s) {
        float4 lo = mr[(s * 32 + k0) >> 2];
        float4 hi = mr[((s * 32 + k0) >> 2) + 1];
        a[s][0] = (_Float16)lo.x; a[s][1] = (_Float16)lo.y;
        a[s][2] = (_Float16)lo.z; a[s][3] = (_Float16)lo.w;
        a[s][4] = (_Float16)hi.x; a[s][5] = (_Float16)hi.y;
        a[s][6] = (_Float16)hi.z; a[s][7] = (_Float16)hi.w;
    }

    f32x4 acc1[4];
#pragma unroll
    for (int n = 0; n < 4; ++n) acc1[n] = (f32x4)0.f;
#pragma unroll
    for (int s = 0; s < 2; ++s)
#pragma unroll
        for (int n = 0; n < 4; ++n)
            acc1[n] = __builtin_amdgcn_mfma_f32_16x16x32_f16(a[s], b1[s][n], acc1[n], 0, 0, 0);

#pragma unroll
    for (int n = 0; n < 4; ++n)
#pragma unroll
        for (int j = 0; j < 4; ++j)
            tl[w][kb * 4 + j][n * 16 + mrow] = (_Float16)fmaxf(acc1[n][j], 0.f);

    half8 a2[2];
#pragma unroll
    for (int s = 0; s < 2; ++s)
        a2[s] = *reinterpret_cast<const half8*>(&tl[w][mrow][s * 32 + k0]);

    f32x4 acc2[4];
#pragma unroll
    for (int n = 0; n < 4; ++n) acc2[n] = (f32x4)0.f;
#pragma unroll
    for (int s = 0; s < 2; ++s)
#pragma unroll
        for (int n = 0; n < 4; ++n)
            acc2[n] = __builtin_amdgcn_mfma_f32_16x16x32_f16(a2[s], b2[s][n], acc2[n], 0, 0, 0);

#pragma unroll
    for (int n = 0; n < 4; ++n)
#pragma unroll
        for (int j = 0; j < 4; ++j) {
            int r = wid * 16 + kb * 4 + j;
            int c = n * 16 + mrow;
            out[(size_t)r * 64 + c] = tanhf(base[(size_t)r * 64 + c] + acc2[n][j]);
        }
}

// ---------------------------------------------------------------------------
extern "C" void kernel_launch(void* const* d_in, const int* in_sizes, int n_in,
                              void* d_out, int out_size, void* d_ws, size_t ws_size,
                              hipStream_t stream)
{
    const float* feature = (const float*)d_in[0];
    const int*   src     = (const int*)d_in[1];
    const int*   dst     = (const int*)d_in[2];
    const float* W_lin   = (const float*)d_in[3];
    const float* W_d1    = (const float*)d_in[4];
    const float* W_d2    = (const float*)d_in[5];
    float* out = (float*)d_out;

    const size_t NODE_F = (size_t)N_NODES * OUT_DIM;   // 6.4M elems

    float*    base     = (float*)d_ws;                          // 25.6 MB
    _Float16* u1h      = (_Float16*)(base + NODE_F);            // 12.8 MB
    float*    m        = (float*)(u1h + NODE_F);                // 25.6 MB
    int*      H        = (int*)(m + NODE_F);                    // 3.2 MB
    int*      Btot     = H + ((size_t)NBUCKETS * NBINBLK + 4);  // NBUCKETS
    int*      node_off = Btot + (NBUCKETS + 4);                 // N_NODES+1
    int*      ebuf     = node_off + (N_NODES + 4);              // 3.2M ints

    // iter 1 collapses: u0 == 0 -> m == 0 -> h == 0 -> u1 = tanh(feature@W_lin)
    int gemm_blocks = (MTILES + 3) / 4;                // 4 waves/block
    gemm_base_tanh<<<gemm_blocks, 256, 0, stream>>>(feature, W_lin, base, u1h);

    bin_hist  <<<NBINBLK, 256, 0, stream>>>(dst, H);
    scan_local<<<NBUCKETS, NBINBLK, 0, stream>>>(H, Btot);
    scan_tot  <<<1, 1024, 0, stream>>>(Btot);
    add_base  <<<NBUCKETS, NBINBLK, 0, stream>>>(H, Btot);
    bin_scatter<<<NBINBLK, 256, 0, stream>>>(src, dst, H, ebuf);
    bucket_sort<<<NBUCKETS, 256, 0, stream>>>(H, ebuf, node_off);

    int gather_blocks = (int)(((size_t)N_NODES * 64 + 255) / 256);   // 25000
    node_gather<<<gather_blocks, 256, 0, stream>>>(
        node_off, ebuf, (const half8*)u1h, m);

    dense_tanh<<<gemm_blocks, 256, 0, stream>>>(m, W_d1, W_d2, base, out);
}

// Round 15
// 162.896 us; speedup vs baseline: 1.2290x; 1.0447x over previous
//
#include <hip/hip_runtime.h>
#include <math.h>

#define N_NODES 100000
#define N_EDGES 3200000
#define IN_DIM  128
#define OUT_DIM 64

#define BSHIFT   7
#define BNODES   128                                   // nodes per bucket
#define NBUCKETS ((N_NODES + BNODES - 1) / BNODES)     // 782
#define NBINBLK  1024
#define CHUNK    (N_EDGES / NBINBLK)                   // 3125 (exact)
#define SEGCAP   6144                                  // max edges/bucket
#define MTILES   (N_NODES / 16)                        // 6250 (exact)
#define GEMM_BLOCKS ((MTILES + 3) / 4)                 // 1563

typedef _Float16 half8 __attribute__((ext_vector_type(8)));
typedef float    f32x4 __attribute__((ext_vector_type(4)));

// XCD-aware swizzle (verified round 11): 128 consecutive logical blocks per
// XCD -> bucket-major ebuf segments write-combine in one L2.
__device__ __forceinline__ int xcd_swz(int i) {
    return (i & 7) * (NBINBLK / 8) + (i >> 3);   // bijective: 1024 = 8*128
}

// ---------------------------------------------------------------------------
// Fused kernel: blocks [0,NBINBLK) run bin_hist; blocks [NBINBLK, +GEMM)
// run the MFMA gemm (base = feature @ W_lin ; u1 = tanh fp16).  The two are
// data-independent and use complementary pipes (LDS-atomic/L2 vs MFMA/HBM),
// so co-residency overlaps what were two serial dispatches.
// Both bodies are byte-identical to the verified round-14 kernels.
// ---------------------------------------------------------------------------
__global__ __launch_bounds__(256) void fused_gemm_hist(
    const float* __restrict__ feature,
    const float* __restrict__ Wlin,     // [128][64] row-major fp32
    float* __restrict__ base,
    _Float16* __restrict__ u1h,
    const int* __restrict__ dst,
    int* __restrict__ H)
{
    __shared__ int h[NBUCKETS];

    if (blockIdx.x < NBINBLK) {
        // ---- bin_hist path (verified round 12) ----
        for (int k = threadIdx.x; k < NBUCKETS; k += 256) h[k] = 0;
        __syncthreads();

        int b = xcd_swz(blockIdx.x);
        int beg = b * CHUNK, end = beg + CHUNK;
        for (int i = beg + threadIdx.x; i < end; i += 256)
            atomicAdd(&h[dst[i] >> BSHIFT], 1);
        __syncthreads();

        for (int k = threadIdx.x; k < NBUCKETS; k += 256)
            H[(size_t)k * NBINBLK + b] = h[k];
        return;
    }

    // ---- gemm path (verified rounds 9-12) ----
    int lane = threadIdx.x & 63;
    int wid  = ((blockIdx.x - NBINBLK) * 256 + threadIdx.x) >> 6;
    if (wid >= MTILES) return;

    int mrow = lane & 15;       // A row / B col / C col
    int kb   = lane >> 4;       // k-block 0..3
    int k0   = kb * 8;

    half8 b[4][4];
#pragma unroll
    for (int s = 0; s < 4; ++s)
#pragma unroll
        for (int n = 0; n < 4; ++n)
#pragma unroll
            for (int j = 0; j < 8; ++j)
                b[s][n][j] = (_Float16)Wlin[(s * 32 + k0 + j) * OUT_DIM + n * 16 + mrow];

    int row = wid * 16 + mrow;
    const float4* fr = reinterpret_cast<const float4*>(feature + (size_t)row * IN_DIM);
    half8 a[4];
#pragma unroll
    for (int s = 0; s < 4; ++s) {
        float4 lo = fr[(s * 32 + k0) >> 2];
        float4 hi = fr[((s * 32 + k0) >> 2) + 1];
        a[s][0] = (_Float16)lo.x; a[s][1] = (_Float16)lo.y;
        a[s][2] = (_Float16)lo.z; a[s][3] = (_Float16)lo.w;
        a[s][4] = (_Float16)hi.x; a[s][5] = (_Float16)hi.y;
        a[s][6] = (_Float16)hi.z; a[s][7] = (_Float16)hi.w;
    }

    f32x4 acc[4];
#pragma unroll
    for (int n = 0; n < 4; ++n) acc[n] = (f32x4)0.f;

#pragma unroll
    for (int s = 0; s < 4; ++s)
#pragma unroll
        for (int n = 0; n < 4; ++n)
            acc[n] = __builtin_amdgcn_mfma_f32_16x16x32_f16(a[s], b[s][n], acc[n], 0, 0, 0);

#pragma unroll
    for (int n = 0; n < 4; ++n)
#pragma unroll
        for (int j = 0; j < 4; ++j) {
            int r = wid * 16 + kb * 4 + j;
            int c = n * 16 + mrow;
            float v = acc[n][j];
            base[(size_t)r * OUT_DIM + c] = v;
            u1h[(size_t)r * OUT_DIM + c] = (_Float16)tanhf(v);
        }
}

// ---------------------------------------------------------------------------
// Hierarchical scan of H (bucket-major), bit-exact.  (verified round 12)
// ---------------------------------------------------------------------------
__global__ __launch_bounds__(NBINBLK) void scan_local(
    int* __restrict__ H, int* __restrict__ Btot)
{
    __shared__ int s[NBINBLK];
    int k = blockIdx.x, t = threadIdx.x;
    int v = H[(size_t)k * NBINBLK + t];
    s[t] = v;
    __syncthreads();
#pragma unroll
    for (int off = 1; off < NBINBLK; off <<= 1) {
        int x = (t >= off) ? s[t - off] : 0;
        __syncthreads();
        s[t] += x;
        __syncthreads();
    }
    H[(size_t)k * NBINBLK + t] = s[t] - v;      // exclusive (local, no base)
    if (t == NBINBLK - 1) Btot[k] = s[t];       // inclusive total
}

__global__ __launch_bounds__(1024) void scan_tot(int* __restrict__ Btot)
{
    __shared__ int s[1024];
    int t = threadIdx.x;
    int v = (t < NBUCKETS) ? Btot[t] : 0;
    s[t] = v;
    __syncthreads();
#pragma unroll
    for (int off = 1; off < 1024; off <<= 1) {
        int x = (t >= off) ? s[t - off] : 0;
        __syncthreads();
        s[t] += x;
        __syncthreads();
    }
    if (t < NBUCKETS) Btot[t] = s[t] - v;       // exclusive bucket base
}

// ---------------------------------------------------------------------------
// bin_scatter: adds the bucket base while loading cursors (replaces the
// add_base dispatch; bit-identical offsets).  XCD swizzle verified r11.
// ---------------------------------------------------------------------------
__global__ __launch_bounds__(256) void bin_scatter(
    const int* __restrict__ src,
    const int* __restrict__ dst,
    const int* __restrict__ H,
    const int* __restrict__ Btot,
    int* __restrict__ ebuf)
{
    __shared__ int cur[NBUCKETS];
    int b = xcd_swz(blockIdx.x);
    for (int k = threadIdx.x; k < NBUCKETS; k += 256)
        cur[k] = H[(size_t)k * NBINBLK + b] + Btot[k];
    __syncthreads();

    int beg = b * CHUNK, end = beg + CHUNK;
    for (int i = beg + threadIdx.x; i < end; i += 256) {
        int d = dst[i];
        int k = d >> BSHIFT;
        int p = atomicAdd(&cur[k], 1);
        // pack: src (17 bits) | dlocal (7 bits) << 17
        ebuf[p] = src[i] | ((d & (BNODES - 1)) << 17);
    }
}

// ---------------------------------------------------------------------------
// bucket_sort: bucket bounds now come from Btot (exclusive bases).
// Body otherwise verified.
// ---------------------------------------------------------------------------
__global__ __launch_bounds__(256) void bucket_sort(
    const int* __restrict__ Btot,
    int* __restrict__ ebuf,
    int* __restrict__ node_off)
{
    __shared__ int seg[SEGCAP];
    __shared__ int cnt[BNODES];
    __shared__ int off[BNODES];
    int k = blockIdx.x;
    int beg = Btot[k];
    int end = (k + 1 < NBUCKETS) ? Btot[k + 1] : N_EDGES;
    int n = end - beg;

    for (int j = threadIdx.x; j < BNODES; j += 256) cnt[j] = 0;
    __syncthreads();

    for (int i = threadIdx.x; i < n; i += 256) {
        int v = ebuf[beg + i];
        seg[i] = v;
        atomicAdd(&cnt[v >> 17], 1);
    }
    __syncthreads();

    if (threadIdx.x == 0) {
        int node0 = k * BNODES;
        int nvalid = N_NODES - node0; if (nvalid > BNODES) nvalid = BNODES;
        int excl = 0;
        for (int j = 0; j < nvalid; ++j) {
            off[j] = excl;
            node_off[node0 + j] = beg + excl;
            excl += cnt[j];
        }
        if (k == NBUCKETS - 1) node_off[N_NODES] = end;
    }
    __syncthreads();

    for (int i = threadIdx.x; i < n; i += 256) {
        int v = seg[i];
        int p = atomicAdd(&off[v >> 17], 1);
        ebuf[beg + p] = v & 0x1FFFF;
    }
}

// ---------------------------------------------------------------------------
// Gather: one wave per node over fp16 u1 rows; contiguous per-q-group
// chunking.  (verified rounds 12-14)
// ---------------------------------------------------------------------------
__global__ __launch_bounds__(256) void node_gather(
    const int* __restrict__ node_off,
    const int* __restrict__ csr,
    const half8* __restrict__ u1v,      // [N_NODES][8]
    float* __restrict__ m)
{
    int wid = (blockIdx.x * 256 + threadIdx.x) >> 6;
    if (wid >= N_NODES) return;
    int lane = threadIdx.x & 63;
    int q = lane >> 3, c = lane & 7;

    int beg = node_off[wid];
    int end = node_off[wid + 1];
    int cnt = end - beg;
    int per = (cnt + 7) >> 3;           // edges per q-group (contiguous)
    int gb  = beg + q * per;
    int ge  = gb + per; if (ge > end) ge = end;

    float acc[8];
#pragma unroll
    for (int i = 0; i < 8; ++i) acc[i] = 0.f;

    int e = gb;
    for (; e + 4 <= ge; e += 4) {
        int s0 = csr[e];
        int s1 = csr[e + 1];
        int s2 = csr[e + 2];
        int s3 = csr[e + 3];
        half8 a = u1v[(size_t)s0 * 8 + c];
        half8 b = u1v[(size_t)s1 * 8 + c];
        half8 g = u1v[(size_t)s2 * 8 + c];
        half8 d = u1v[(size_t)s3 * 8 + c];
#pragma unroll
        for (int i = 0; i < 8; ++i)
            acc[i] += ((float)a[i] + (float)b[i]) + ((float)g[i] + (float)d[i]);
    }
    for (; e < ge; ++e) {
        half8 a = u1v[(size_t)csr[e] * 8 + c];
#pragma unroll
        for (int i = 0; i < 8; ++i) acc[i] += (float)a[i];
    }

    // reduce across the 8 q-groups (lane bits 3,4,5)
#pragma unroll
    for (int i = 0; i < 8; ++i) {
        acc[i] += __shfl_xor(acc[i], 8);
        acc[i] += __shfl_xor(acc[i], 16);
        acc[i] += __shfl_xor(acc[i], 32);
    }

    if (q == 0) {
        float4* mr = reinterpret_cast<float4*>(m + (size_t)wid * OUT_DIM + c * 8);
        mr[0] = make_float4(acc[0], acc[1], acc[2], acc[3]);
        mr[1] = make_float4(acc[4], acc[5], acc[6], acc[7]);
    }
}

// ---------------------------------------------------------------------------
// Kernel 3 (MFMA): out = tanh(base + relu(m @ W_d1) @ W_d2)
// (verified round 12)
// ---------------------------------------------------------------------------
__global__ __launch_bounds__(256) void dense_tanh(
    const float* __restrict__ m,
    const float* __restrict__ W1,       // [64][64]
    const float* __restrict__ W2,       // [64][64]
    const float* __restrict__ base,
    float* __restrict__ out)
{
    __shared__ _Float16 tl[4][16][72];  // 9 KB: per-wave transpose tile
    int lane = threadIdx.x & 63;
    int w    = threadIdx.x >> 6;        // wave in block
    int wid  = (blockIdx.x * 256 + threadIdx.x) >> 6;
    if (wid >= MTILES) return;

    int mrow = lane & 15;
    int kb   = lane >> 4;
    int k0   = kb * 8;

    half8 b1[2][4], b2[2][4];
#pragma unroll
    for (int s = 0; s < 2; ++s)
#pragma unroll
        for (int n = 0; n < 4; ++n)
#pragma unroll
            for (int j = 0; j < 8; ++j) {
                b1[s][n][j] = (_Float16)W1[(s * 32 + k0 + j) * 64 + n * 16 + mrow];
                b2[s][n][j] = (_Float16)W2[(s * 32 + k0 + j) * 64 + n * 16 + mrow];
            }

    int row = wid * 16 + mrow;
    const float4* mr = reinterpret_cast<const float4*>(m + (size_t)row * 64);
    half8 a[2];
#pragma unroll
    for (int s = 0; s < 2; ++s) {
        float4 lo = mr[(s * 32 + k0) >> 2];
        float4 hi = mr[((s * 32 + k0) >> 2) + 1];
        a[s][0] = (_Float16)lo.x; a[s][1] = (_Float16)lo.y;
        a[s][2] = (_Float16)lo.z; a[s][3] = (_Float16)lo.w;
        a[s][4] = (_Float16)hi.x; a[s][5] = (_Float16)hi.y;
        a[s][6] = (_Float16)hi.z; a[s][7] = (_Float16)hi.w;
    }

    f32x4 acc1[4];
#pragma unroll
    for (int n = 0; n < 4; ++n) acc1[n] = (f32x4)0.f;
#pragma unroll
    for (int s = 0; s < 2; ++s)
#pragma unroll
        for (int n = 0; n < 4; ++n)
            acc1[n] = __builtin_amdgcn_mfma_f32_16x16x32_f16(a[s], b1[s][n], acc1[n], 0, 0, 0);

#pragma unroll
    for (int n = 0; n < 4; ++n)
#pragma unroll
        for (int j = 0; j < 4; ++j)
            tl[w][kb * 4 + j][n * 16 + mrow] = (_Float16)fmaxf(acc1[n][j], 0.f);

    half8 a2[2];
#pragma unroll
    for (int s = 0; s < 2; ++s)
        a2[s] = *reinterpret_cast<const half8*>(&tl[w][mrow][s * 32 + k0]);

    f32x4 acc2[4];
#pragma unroll
    for (int n = 0; n < 4; ++n) acc2[n] = (f32x4)0.f;
#pragma unroll
    for (int s = 0; s < 2; ++s)
#pragma unroll
        for (int n = 0; n < 4; ++n)
            acc2[n] = __builtin_amdgcn_mfma_f32_16x16x32_f16(a2[s], b2[s][n], acc2[n], 0, 0, 0);

#pragma unroll
    for (int n = 0; n < 4; ++n)
#pragma unroll
        for (int j = 0; j < 4; ++j) {
            int r = wid * 16 + kb * 4 + j;
            int c = n * 16 + mrow;
            out[(size_t)r * 64 + c] = tanhf(base[(size_t)r * 64 + c] + acc2[n][j]);
        }
}

// ---------------------------------------------------------------------------
extern "C" void kernel_launch(void* const* d_in, const int* in_sizes, int n_in,
                              void* d_out, int out_size, void* d_ws, size_t ws_size,
                              hipStream_t stream)
{
    const float* feature = (const float*)d_in[0];
    const int*   src     = (const int*)d_in[1];
    const int*   dst     = (const int*)d_in[2];
    const float* W_lin   = (const float*)d_in[3];
    const float* W_d1    = (const float*)d_in[4];
    const float* W_d2    = (const float*)d_in[5];
    float* out = (float*)d_out;

    const size_t NODE_F = (size_t)N_NODES * OUT_DIM;   // 6.4M elems

    float*    base     = (float*)d_ws;                          // 25.6 MB
    _Float16* u1h      = (_Float16*)(base + NODE_F);            // 12.8 MB
    float*    m        = (float*)(u1h + NODE_F);                // 25.6 MB
    int*      H        = (int*)(m + NODE_F);                    // 3.2 MB
    int*      Btot     = H + ((size_t)NBUCKETS * NBINBLK + 4);  // NBUCKETS
    int*      node_off = Btot + (NBUCKETS + 4);                 // N_NODES+1
    int*      ebuf     = node_off + (N_NODES + 4);              // 3.2M ints

    // iter 1 collapses: u0 == 0 -> m == 0 -> h == 0 -> u1 = tanh(feature@W_lin)
    fused_gemm_hist<<<NBINBLK + GEMM_BLOCKS, 256, 0, stream>>>(
        feature, W_lin, base, u1h, dst, H);

    scan_local<<<NBUCKETS, NBINBLK, 0, stream>>>(H, Btot);
    scan_tot  <<<1, 1024, 0, stream>>>(Btot);
    bin_scatter<<<NBINBLK, 256, 0, stream>>>(src, dst, H, Btot, ebuf);
    bucket_sort<<<NBUCKETS, 256, 0, stream>>>(Btot, ebuf, node_off);

    int gather_blocks = (int)(((size_t)N_NODES * 64 + 255) / 256);   // 25000
    node_gather<<<gather_blocks, 256, 0, stream>>>(
        node_off, ebuf, (const half8*)u1h, m);

    dense_tanh<<<GEMM_BLOCKS, 256, 0, stream>>>(m, W_d1, W_d2, base, out);
}

// Round 16
// 160.360 us; speedup vs baseline: 1.2484x; 1.0158x over previous
//
#include <hip/hip_runtime.h>
#include <math.h>

#define N_NODES 100000
#define N_EDGES 3200000
#define IN_DIM  128
#define OUT_DIM 64

#define BSHIFT   7
#define BNODES   128                                   // nodes per bucket
#define NBUCKETS ((N_NODES + BNODES - 1) / BNODES)     // 782
#define NBINBLK  1024
#define CHUNK    (N_EDGES / NBINBLK)                   // 3125 (exact)
#define SEGCAP   6144                                  // max edges/bucket
#define MTILES   (N_NODES / 16)                        // 6250 (exact)
#define GEMM_BLOCKS ((MTILES + 3) / 4)                 // 1563

typedef _Float16 half8 __attribute__((ext_vector_type(8)));
typedef float    f32x4 __attribute__((ext_vector_type(4)));

// XCD-aware swizzle (verified round 11): 128 consecutive logical blocks per
// XCD -> bucket-major ebuf segments write-combine in one L2.
__device__ __forceinline__ int xcd_swz(int i) {
    return (i & 7) * (NBINBLK / 8) + (i >> 3);   // bijective: 1024 = 8*128
}

// ---------------------------------------------------------------------------
// Fused kernel: blocks [0,NBINBLK) run bin_hist; blocks [NBINBLK, +GEMM)
// run the MFMA gemm.  (verified round 15)
// ---------------------------------------------------------------------------
__global__ __launch_bounds__(256) void fused_gemm_hist(
    const float* __restrict__ feature,
    const float* __restrict__ Wlin,     // [128][64] row-major fp32
    float* __restrict__ base,
    _Float16* __restrict__ u1h,
    const int* __restrict__ dst,
    int* __restrict__ H)
{
    __shared__ int h[NBUCKETS];

    if (blockIdx.x < NBINBLK) {
        // ---- bin_hist path (verified round 12) ----
        for (int k = threadIdx.x; k < NBUCKETS; k += 256) h[k] = 0;
        __syncthreads();

        int b = xcd_swz(blockIdx.x);
        int beg = b * CHUNK, end = beg + CHUNK;
        for (int i = beg + threadIdx.x; i < end; i += 256)
            atomicAdd(&h[dst[i] >> BSHIFT], 1);
        __syncthreads();

        for (int k = threadIdx.x; k < NBUCKETS; k += 256)
            H[(size_t)k * NBINBLK + b] = h[k];
        return;
    }

    // ---- gemm path (verified rounds 9-12) ----
    int lane = threadIdx.x & 63;
    int wid  = ((blockIdx.x - NBINBLK) * 256 + threadIdx.x) >> 6;
    if (wid >= MTILES) return;

    int mrow = lane & 15;       // A row / B col / C col
    int kb   = lane >> 4;       // k-block 0..3
    int k0   = kb * 8;

    half8 b[4][4];
#pragma unroll
    for (int s = 0; s < 4; ++s)
#pragma unroll
        for (int n = 0; n < 4; ++n)
#pragma unroll
            for (int j = 0; j < 8; ++j)
                b[s][n][j] = (_Float16)Wlin[(s * 32 + k0 + j) * OUT_DIM + n * 16 + mrow];

    int row = wid * 16 + mrow;
    const float4* fr = reinterpret_cast<const float4*>(feature + (size_t)row * IN_DIM);
    half8 a[4];
#pragma unroll
    for (int s = 0; s < 4; ++s) {
        float4 lo = fr[(s * 32 + k0) >> 2];
        float4 hi = fr[((s * 32 + k0) >> 2) + 1];
        a[s][0] = (_Float16)lo.x; a[s][1] = (_Float16)lo.y;
        a[s][2] = (_Float16)lo.z; a[s][3] = (_Float16)lo.w;
        a[s][4] = (_Float16)hi.x; a[s][5] = (_Float16)hi.y;
        a[s][6] = (_Float16)hi.z; a[s][7] = (_Float16)hi.w;
    }

    f32x4 acc[4];
#pragma unroll
    for (int n = 0; n < 4; ++n) acc[n] = (f32x4)0.f;

#pragma unroll
    for (int s = 0; s < 4; ++s)
#pragma unroll
        for (int n = 0; n < 4; ++n)
            acc[n] = __builtin_amdgcn_mfma_f32_16x16x32_f16(a[s], b[s][n], acc[n], 0, 0, 0);

#pragma unroll
    for (int n = 0; n < 4; ++n)
#pragma unroll
        for (int j = 0; j < 4; ++j) {
            int r = wid * 16 + kb * 4 + j;
            int c = n * 16 + mrow;
            float v = acc[n][j];
            base[(size_t)r * OUT_DIM + c] = v;
            u1h[(size_t)r * OUT_DIM + c] = (_Float16)tanhf(v);
        }
}

// ---------------------------------------------------------------------------
// Hierarchical scan of H (bucket-major), bit-exact.  (verified round 12)
// ---------------------------------------------------------------------------
__global__ __launch_bounds__(NBINBLK) void scan_local(
    int* __restrict__ H, int* __restrict__ Btot)
{
    __shared__ int s[NBINBLK];
    int k = blockIdx.x, t = threadIdx.x;
    int v = H[(size_t)k * NBINBLK + t];
    s[t] = v;
    __syncthreads();
#pragma unroll
    for (int off = 1; off < NBINBLK; off <<= 1) {
        int x = (t >= off) ? s[t - off] : 0;
        __syncthreads();
        s[t] += x;
        __syncthreads();
    }
    H[(size_t)k * NBINBLK + t] = s[t] - v;      // exclusive (local, no base)
    if (t == NBINBLK - 1) Btot[k] = s[t];       // inclusive total
}

__global__ __launch_bounds__(1024) void scan_tot(int* __restrict__ Btot)
{
    __shared__ int s[1024];
    int t = threadIdx.x;
    int v = (t < NBUCKETS) ? Btot[t] : 0;
    s[t] = v;
    __syncthreads();
#pragma unroll
    for (int off = 1; off < 1024; off <<= 1) {
        int x = (t >= off) ? s[t - off] : 0;
        __syncthreads();
        s[t] += x;
        __syncthreads();
    }
    if (t < NBUCKETS) Btot[t] = s[t] - v;       // exclusive bucket base
}

// ---------------------------------------------------------------------------
// bin_scatter: 512 threads/block (round 16) -- 1024 blocks x 8 waves = 8192
// waves fills the chip; per-thread latency chain halves.  Adds bucket base
// while loading cursors (verified round 15).
// ---------------------------------------------------------------------------
__global__ __launch_bounds__(512) void bin_scatter(
    const int* __restrict__ src,
    const int* __restrict__ dst,
    const int* __restrict__ H,
    const int* __restrict__ Btot,
    int* __restrict__ ebuf)
{
    __shared__ int cur[NBUCKETS];
    int b = xcd_swz(blockIdx.x);
    for (int k = threadIdx.x; k < NBUCKETS; k += 512)
        cur[k] = H[(size_t)k * NBINBLK + b] + Btot[k];
    __syncthreads();

    int beg = b * CHUNK, end = beg + CHUNK;
    for (int i = beg + threadIdx.x; i < end; i += 512) {
        int d = dst[i];
        int k = d >> BSHIFT;
        int p = atomicAdd(&cur[k], 1);
        // pack: src (17 bits) | dlocal (7 bits) << 17
        ebuf[p] = src[i] | ((d & (BNODES - 1)) << 17);
    }
}

// ---------------------------------------------------------------------------
// bucket_sort: 512 threads/block (round 16); bounds from Btot (verified
// round 15).  LDS 25.6 KB -> 4 blocks/CU x 8 waves = 32 waves/CU (cap).
// ---------------------------------------------------------------------------
__global__ __launch_bounds__(512) void bucket_sort(
    const int* __restrict__ Btot,
    int* __restrict__ ebuf,
    int* __restrict__ node_off)
{
    __shared__ int seg[SEGCAP];
    __shared__ int cnt[BNODES];
    __shared__ int off[BNODES];
    int k = blockIdx.x;
    int beg = Btot[k];
    int end = (k + 1 < NBUCKETS) ? Btot[k + 1] : N_EDGES;
    int n = end - beg;

    for (int j = threadIdx.x; j < BNODES; j += 512) cnt[j] = 0;
    __syncthreads();

    for (int i = threadIdx.x; i < n; i += 512) {
        int v = ebuf[beg + i];
        seg[i] = v;
        atomicAdd(&cnt[v >> 17], 1);
    }
    __syncthreads();

    if (threadIdx.x == 0) {
        int node0 = k * BNODES;
        int nvalid = N_NODES - node0; if (nvalid > BNODES) nvalid = BNODES;
        int excl = 0;
        for (int j = 0; j < nvalid; ++j) {
            off[j] = excl;
            node_off[node0 + j] = beg + excl;
            excl += cnt[j];
        }
        if (k == NBUCKETS - 1) node_off[N_NODES] = end;
    }
    __syncthreads();

    for (int i = threadIdx.x; i < n; i += 512) {
        int v = seg[i];
        int p = atomicAdd(&off[v >> 17], 1);
        ebuf[beg + p] = v & 0x1FFFF;
    }
}

// ---------------------------------------------------------------------------
// Gather: one wave per node over fp16 u1 rows; contiguous per-q-group
// chunking.  (verified rounds 12-15)
// ---------------------------------------------------------------------------
__global__ __launch_bounds__(256) void node_gather(
    const int* __restrict__ node_off,
    const int* __restrict__ csr,
    const half8* __restrict__ u1v,      // [N_NODES][8]
    float* __restrict__ m)
{
    int wid = (blockIdx.x * 256 + threadIdx.x) >> 6;
    if (wid >= N_NODES) return;
    int lane = threadIdx.x & 63;
    int q = lane >> 3, c = lane & 7;

    int beg = node_off[wid];
    int end = node_off[wid + 1];
    int cnt = end - beg;
    int per = (cnt + 7) >> 3;           // edges per q-group (contiguous)
    int gb  = beg + q * per;
    int ge  = gb + per; if (ge > end) ge = end;

    float acc[8];
#pragma unroll
    for (int i = 0; i < 8; ++i) acc[i] = 0.f;

    int e = gb;
    for (; e + 4 <= ge; e += 4) {
        int s0 = csr[e];
        int s1 = csr[e + 1];
        int s2 = csr[e + 2];
        int s3 = csr[e + 3];
        half8 a = u1v[(size_t)s0 * 8 + c];
        half8 b = u1v[(size_t)s1 * 8 + c];
        half8 g = u1v[(size_t)s2 * 8 + c];
        half8 d = u1v[(size_t)s3 * 8 + c];
#pragma unroll
        for (int i = 0; i < 8; ++i)
            acc[i] += ((float)a[i] + (float)b[i]) + ((float)g[i] + (float)d[i]);
    }
    for (; e < ge; ++e) {
        half8 a = u1v[(size_t)csr[e] * 8 + c];
#pragma unroll
        for (int i = 0; i < 8; ++i) acc[i] += (float)a[i];
    }

    // reduce across the 8 q-groups (lane bits 3,4,5)
#pragma unroll
    for (int i = 0; i < 8; ++i) {
        acc[i] += __shfl_xor(acc[i], 8);
        acc[i] += __shfl_xor(acc[i], 16);
        acc[i] += __shfl_xor(acc[i], 32);
    }

    if (q == 0) {
        float4* mr = reinterpret_cast<float4*>(m + (size_t)wid * OUT_DIM + c * 8);
        mr[0] = make_float4(acc[0], acc[1], acc[2], acc[3]);
        mr[1] = make_float4(acc[4], acc[5], acc[6], acc[7]);
    }
}

// ---------------------------------------------------------------------------
// Kernel 3 (MFMA): out = tanh(base + relu(m @ W_d1) @ W_d2)
// (verified round 12)
// ---------------------------------------------------------------------------
__global__ __launch_bounds__(256) void dense_tanh(
    const float* __restrict__ m,
    const float* __restrict__ W1,       // [64][64]
    const float* __restrict__ W2,       // [64][64]
    const float* __restrict__ base,
    float* __restrict__ out)
{
    __shared__ _Float16 tl[4][16][72];  // 9 KB: per-wave transpose tile
    int lane = threadIdx.x & 63;
    int w    = threadIdx.x >> 6;        // wave in block
    int wid  = (blockIdx.x * 256 + threadIdx.x) >> 6;
    if (wid >= MTILES) return;

    int mrow = lane & 15;
    int kb   = lane >> 4;
    int k0   = kb * 8;

    half8 b1[2][4], b2[2][4];
#pragma unroll
    for (int s = 0; s < 2; ++s)
#pragma unroll
        for (int n = 0; n < 4; ++n)
#pragma unroll
            for (int j = 0; j < 8; ++j) {
                b1[s][n][j] = (_Float16)W1[(s * 32 + k0 + j) * 64 + n * 16 + mrow];
                b2[s][n][j] = (_Float16)W2[(s * 32 + k0 + j) * 64 + n * 16 + mrow];
            }

    int row = wid * 16 + mrow;
    const float4* mr = reinterpret_cast<const float4*>(m + (size_t)row * 64);
    half8 a[2];
#pragma unroll
    for (int s = 0; s < 2; ++s) {
        float4 lo = mr[(s * 32 + k0) >> 2];
        float4 hi = mr[((s * 32 + k0) >> 2) + 1];
        a[s][0] = (_Float16)lo.x; a[s][1] = (_Float16)lo.y;
        a[s][2] = (_Float16)lo.z; a[s][3] = (_Float16)lo.w;
        a[s][4] = (_Float16)hi.x; a[s][5] = (_Float16)hi.y;
        a[s][6] = (_Float16)hi.z; a[s][7] = (_Float16)hi.w;
    }

    f32x4 acc1[4];
#pragma unroll
    for (int n = 0; n < 4; ++n) acc1[n] = (f32x4)0.f;
#pragma unroll
    for (int s = 0; s < 2; ++s)
#pragma unroll
        for (int n = 0; n < 4; ++n)
            acc1[n] = __builtin_amdgcn_mfma_f32_16x16x32_f16(a[s], b1[s][n], acc1[n], 0, 0, 0);

#pragma unroll
    for (int n = 0; n < 4; ++n)
#pragma unroll
        for (int j = 0; j < 4; ++j)
            tl[w][kb * 4 + j][n * 16 + mrow] = (_Float16)fmaxf(acc1[n][j], 0.f);

    half8 a2[2];
#pragma unroll
    for (int s = 0; s < 2; ++s)
        a2[s] = *reinterpret_cast<const half8*>(&tl[w][mrow][s * 32 + k0]);

    f32x4 acc2[4];
#pragma unroll
    for (int n = 0; n < 4; ++n) acc2[n] = (f32x4)0.f;
#pragma unroll
    for (int s = 0; s < 2; ++s)
#pragma unroll
        for (int n = 0; n < 4; ++n)
            acc2[n] = __builtin_amdgcn_mfma_f32_16x16x32_f16(a2[s], b2[s][n], acc2[n], 0, 0, 0);

#pragma unroll
    for (int n = 0; n < 4; ++n)
#pragma unroll
        for (int j = 0; j < 4; ++j) {
            int r = wid * 16 + kb * 4 + j;
            int c = n * 16 + mrow;
            out[(size_t)r * 64 + c] = tanhf(base[(size_t)r * 64 + c] + acc2[n][j]);
        }
}

// ---------------------------------------------------------------------------
extern "C" void kernel_launch(void* const* d_in, const int* in_sizes, int n_in,
                              void* d_out, int out_size, void* d_ws, size_t ws_size,
                              hipStream_t stream)
{
    const float* feature = (const float*)d_in[0];
    const int*   src     = (const int*)d_in[1];
    const int*   dst     = (const int*)d_in[2];
    const float* W_lin   = (const float*)d_in[3];
    const float* W_d1    = (const float*)d_in[4];
    const float* W_d2    = (const float*)d_in[5];
    float* out = (float*)d_out;

    const size_t NODE_F = (size_t)N_NODES * OUT_DIM;   // 6.4M elems

    float*    base     = (float*)d_ws;                          // 25.6 MB
    _Float16* u1h      = (_Float16*)(base + NODE_F);            // 12.8 MB
    float*    m        = (float*)(u1h + NODE_F);                // 25.6 MB
    int*      H        = (int*)(m + NODE_F);                    // 3.2 MB
    int*      Btot     = H + ((size_t)NBUCKETS * NBINBLK + 4);  // NBUCKETS
    int*      node_off = Btot + (NBUCKETS + 4);                 // N_NODES+1
    int*      ebuf     = node_off + (N_NODES + 4);              // 3.2M ints

    // iter 1 collapses: u0 == 0 -> m == 0 -> h == 0 -> u1 = tanh(feature@W_lin)
    fused_gemm_hist<<<NBINBLK + GEMM_BLOCKS, 256, 0, stream>>>(
        feature, W_lin, base, u1h, dst, H);

    scan_local<<<NBUCKETS, NBINBLK, 0, stream>>>(H, Btot);
    scan_tot  <<<1, 1024, 0, stream>>>(Btot);
    bin_scatter<<<NBINBLK, 512, 0, stream>>>(src, dst, H, Btot, ebuf);
    bucket_sort<<<NBUCKETS, 512, 0, stream>>>(Btot, ebuf, node_off);

    int gather_blocks = (int)(((size_t)N_NODES * 64 + 255) / 256);   // 25000
    node_gather<<<gather_blocks, 256, 0, stream>>>(
        node_off, ebuf, (const half8*)u1h, m);

    dense_tanh<<<GEMM_BLOCKS, 256, 0, stream>>>(m, W_d1, W_d2, base, out);
}

// Round 17
// 157.416 us; speedup vs baseline: 1.2718x; 1.0187x over previous
//
#include <hip/hip_runtime.h>
#include <math.h>

#define N_NODES 100000
#define N_EDGES 3200000
#define IN_DIM  128
#define OUT_DIM 64

#define BSHIFT   7
#define BNODES   128                                   // nodes per bucket
#define NBUCKETS ((N_NODES + BNODES - 1) / BNODES)     // 782
#define NBINBLK  1024
#define CHUNK    (N_EDGES / NBINBLK)                   // 3125 (exact)
#define SEGCAP   6144                                  // max edges/bucket
#define MTILES   (N_NODES / 16)                        // 6250 (exact)
#define GEMM_BLOCKS ((MTILES + 3) / 4)                 // 1563

typedef _Float16 half8 __attribute__((ext_vector_type(8)));
typedef float    f32x4 __attribute__((ext_vector_type(4)));

// XCD-aware swizzle (verified round 11): 128 consecutive logical blocks per
// XCD -> bucket-major ebuf segments write-combine in one L2.
__device__ __forceinline__ int xcd_swz(int i) {
    return (i & 7) * (NBINBLK / 8) + (i >> 3);   // bijective: 1024 = 8*128
}

// Exclusive scan of Btot[0..NBUCKETS) into LDS bs[] (512 threads).
// Integer Hillis-Steele -- bit-identical to the old scan_tot dispatch.
__device__ __forceinline__ void scan_btot(
    const int* __restrict__ Btot, int* bs, int* tmp)
{
    int t = threadIdx.x;
    const int C = (NBUCKETS + 511) / 512;   // 2
    int b0 = t * C;
    int s = 0;
#pragma unroll
    for (int i = 0; i < C; ++i) {
        int idx = b0 + i;
        int v = (idx < NBUCKETS) ? Btot[idx] : 0;
        if (idx < NBUCKETS) bs[idx] = v;
        s += v;
    }
    tmp[t] = s;
    __syncthreads();
#pragma unroll
    for (int o = 1; o < 512; o <<= 1) {
        int v = (t >= o) ? tmp[t - o] : 0;
        __syncthreads();
        tmp[t] += v;
        __syncthreads();
    }
    int excl = (t == 0) ? 0 : tmp[t - 1];
#pragma unroll
    for (int i = 0; i < C; ++i) {
        int idx = b0 + i;
        if (idx < NBUCKETS) { int v = bs[idx]; bs[idx] = excl; excl += v; }
    }
    __syncthreads();
}

// ---------------------------------------------------------------------------
// Fused kernel: blocks [0,NBINBLK) run bin_hist; blocks [NBINBLK, +GEMM)
// run the MFMA gemm.  (verified round 15)
// ---------------------------------------------------------------------------
__global__ __launch_bounds__(256) void fused_gemm_hist(
    const float* __restrict__ feature,
    const float* __restrict__ Wlin,     // [128][64] row-major fp32
    float* __restrict__ base,
    _Float16* __restrict__ u1h,
    const int* __restrict__ dst,
    int* __restrict__ H)
{
    __shared__ int h[NBUCKETS];

    if (blockIdx.x < NBINBLK) {
        // ---- bin_hist path (verified round 12) ----
        for (int k = threadIdx.x; k < NBUCKETS; k += 256) h[k] = 0;
        __syncthreads();

        int b = xcd_swz(blockIdx.x);
        int beg = b * CHUNK, end = beg + CHUNK;
        for (int i = beg + threadIdx.x; i < end; i += 256)
            atomicAdd(&h[dst[i] >> BSHIFT], 1);
        __syncthreads();

        for (int k = threadIdx.x; k < NBUCKETS; k += 256)
            H[(size_t)k * NBINBLK + b] = h[k];
        return;
    }

    // ---- gemm path (verified rounds 9-12) ----
    int lane = threadIdx.x & 63;
    int wid  = ((blockIdx.x - NBINBLK) * 256 + threadIdx.x) >> 6;
    if (wid >= MTILES) return;

    int mrow = lane & 15;       // A row / B col / C col
    int kb   = lane >> 4;       // k-block 0..3
    int k0   = kb * 8;

    half8 b[4][4];
#pragma unroll
    for (int s = 0; s < 4; ++s)
#pragma unroll
        for (int n = 0; n < 4; ++n)
#pragma unroll
            for (int j = 0; j < 8; ++j)
                b[s][n][j] = (_Float16)Wlin[(s * 32 + k0 + j) * OUT_DIM + n * 16 + mrow];

    int row = wid * 16 + mrow;
    const float4* fr = reinterpret_cast<const float4*>(feature + (size_t)row * IN_DIM);
    half8 a[4];
#pragma unroll
    for (int s = 0; s < 4; ++s) {
        float4 lo = fr[(s * 32 + k0) >> 2];
        float4 hi = fr[((s * 32 + k0) >> 2) + 1];
        a[s][0] = (_Float16)lo.x; a[s][1] = (_Float16)lo.y;
        a[s][2] = (_Float16)lo.z; a[s][3] = (_Float16)lo.w;
        a[s][4] = (_Float16)hi.x; a[s][5] = (_Float16)hi.y;
        a[s][6] = (_Float16)hi.z; a[s][7] = (_Float16)hi.w;
    }

    f32x4 acc[4];
#pragma unroll
    for (int n = 0; n < 4; ++n) acc[n] = (f32x4)0.f;

#pragma unroll
    for (int s = 0; s < 4; ++s)
#pragma unroll
        for (int n = 0; n < 4; ++n)
            acc[n] = __builtin_amdgcn_mfma_f32_16x16x32_f16(a[s], b[s][n], acc[n], 0, 0, 0);

#pragma unroll
    for (int n = 0; n < 4; ++n)
#pragma unroll
        for (int j = 0; j < 4; ++j) {
            int r = wid * 16 + kb * 4 + j;
            int c = n * 16 + mrow;
            float v = acc[n][j];
            base[(size_t)r * OUT_DIM + c] = v;
            u1h[(size_t)r * OUT_DIM + c] = (_Float16)tanhf(v);
        }
}

// ---------------------------------------------------------------------------
// scan_local: per-bucket exclusive scan of H row; Btot[k] = inclusive total.
// (verified round 12; Btot now stays raw -- consumers re-derive the base)
// ---------------------------------------------------------------------------
__global__ __launch_bounds__(NBINBLK) void scan_local(
    int* __restrict__ H, int* __restrict__ Btot)
{
    __shared__ int s[NBINBLK];
    int k = blockIdx.x, t = threadIdx.x;
    int v = H[(size_t)k * NBINBLK + t];
    s[t] = v;
    __syncthreads();
#pragma unroll
    for (int off = 1; off < NBINBLK; off <<= 1) {
        int x = (t >= off) ? s[t - off] : 0;
        __syncthreads();
        s[t] += x;
        __syncthreads();
    }
    H[(size_t)k * NBINBLK + t] = s[t] - v;      // exclusive (local, no base)
    if (t == NBINBLK - 1) Btot[k] = s[t];       // inclusive total
}

// ---------------------------------------------------------------------------
// bin_scatter: derives bucket bases from raw Btot in-prologue (replaces the
// scan_tot dispatch; bit-identical offsets).  512 threads (verified r16).
// ---------------------------------------------------------------------------
__global__ __launch_bounds__(512) void bin_scatter(
    const int* __restrict__ src,
    const int* __restrict__ dst,
    const int* __restrict__ H,
    const int* __restrict__ Btot,
    int* __restrict__ ebuf)
{
    __shared__ int cur[NBUCKETS];
    __shared__ int bs[NBUCKETS];
    __shared__ int tmp[512];

    scan_btot(Btot, bs, tmp);

    int b = xcd_swz(blockIdx.x);
    for (int k = threadIdx.x; k < NBUCKETS; k += 512)
        cur[k] = H[(size_t)k * NBINBLK + b] + bs[k];
    __syncthreads();

    int beg = b * CHUNK, end = beg + CHUNK;
    for (int i = beg + threadIdx.x; i < end; i += 512) {
        int d = dst[i];
        int k = d >> BSHIFT;
        int p = atomicAdd(&cur[k], 1);
        // pack: src (17 bits) | dlocal (7 bits) << 17
        ebuf[p] = src[i] | ((d & (BNODES - 1)) << 17);
    }
}

// ---------------------------------------------------------------------------
// bucket_sort: bucket bounds from in-prologue Btot scan.  512 threads.
// ---------------------------------------------------------------------------
__global__ __launch_bounds__(512) void bucket_sort(
    const int* __restrict__ Btot,
    int* __restrict__ ebuf,
    int* __restrict__ node_off)
{
    __shared__ int seg[SEGCAP];
    __shared__ int cnt[BNODES];
    __shared__ int off[BNODES];
    __shared__ int bs[NBUCKETS];
    __shared__ int tmp[512];

    scan_btot(Btot, bs, tmp);

    int k = blockIdx.x;
    int beg = bs[k];
    int end = (k + 1 < NBUCKETS) ? bs[k + 1] : N_EDGES;
    int n = end - beg;

    for (int j = threadIdx.x; j < BNODES; j += 512) cnt[j] = 0;
    __syncthreads();

    for (int i = threadIdx.x; i < n; i += 512) {
        int v = ebuf[beg + i];
        seg[i] = v;
        atomicAdd(&cnt[v >> 17], 1);
    }
    __syncthreads();

    if (threadIdx.x == 0) {
        int node0 = k * BNODES;
        int nvalid = N_NODES - node0; if (nvalid > BNODES) nvalid = BNODES;
        int excl = 0;
        for (int j = 0; j < nvalid; ++j) {
            off[j] = excl;
            node_off[node0 + j] = beg + excl;
            excl += cnt[j];
        }
        if (k == NBUCKETS - 1) node_off[N_NODES] = end;
    }
    __syncthreads();

    for (int i = threadIdx.x; i < n; i += 512) {
        int v = seg[i];
        int p = atomicAdd(&off[v >> 17], 1);
        ebuf[beg + p] = v & 0x1FFFF;
    }
}

// ---------------------------------------------------------------------------
// Gather: one wave per node over fp16 u1 rows; contiguous per-q-group
// chunking (verified r12-16).  Round 17: m written as fp16 half8 -- the
// fp32->fp16 cast moved here from dense_tanh's A-frag load, so the MFMA
// inputs are BIT-IDENTICAL; traffic drops 25.6 -> 12.8 MB.
// ---------------------------------------------------------------------------
__global__ __launch_bounds__(256) void node_gather(
    const int* __restrict__ node_off,
    const int* __restrict__ csr,
    const half8* __restrict__ u1v,      // [N_NODES][8]
    half8* __restrict__ mh)             // [N_NODES][8] fp16
{
    int wid = (blockIdx.x * 256 + threadIdx.x) >> 6;
    if (wid >= N_NODES) return;
    int lane = threadIdx.x & 63;
    int q = lane >> 3, c = lane & 7;

    int beg = node_off[wid];
    int end = node_off[wid + 1];
    int cnt = end - beg;
    int per = (cnt + 7) >> 3;           // edges per q-group (contiguous)
    int gb  = beg + q * per;
    int ge  = gb + per; if (ge > end) ge = end;

    float acc[8];
#pragma unroll
    for (int i = 0; i < 8; ++i) acc[i] = 0.f;

    int e = gb;
    for (; e + 4 <= ge; e += 4) {
        int s0 = csr[e];
        int s1 = csr[e + 1];
        int s2 = csr[e + 2];
        int s3 = csr[e + 3];
        half8 a = u1v[(size_t)s0 * 8 + c];
        half8 b = u1v[(size_t)s1 * 8 + c];
        half8 g = u1v[(size_t)s2 * 8 + c];
        half8 d = u1v[(size_t)s3 * 8 + c];
#pragma unroll
        for (int i = 0; i < 8; ++i)
            acc[i] += ((float)a[i] + (float)b[i]) + ((float)g[i] + (float)d[i]);
    }
    for (; e < ge; ++e) {
        half8 a = u1v[(size_t)csr[e] * 8 + c];
#pragma unroll
        for (int i = 0; i < 8; ++i) acc[i] += (float)a[i];
    }

    // reduce across the 8 q-groups (lane bits 3,4,5)
#pragma unroll
    for (int i = 0; i < 8; ++i) {
        acc[i] += __shfl_xor(acc[i], 8);
        acc[i] += __shfl_xor(acc[i], 16);
        acc[i] += __shfl_xor(acc[i], 32);
    }

    if (q == 0) {
        half8 hv;
#pragma unroll
        for (int i = 0; i < 8; ++i) hv[i] = (_Float16)acc[i];
        mh[(size_t)wid * 8 + c] = hv;   // 16 B/lane, 128 B/row coalesced
    }
}

// ---------------------------------------------------------------------------
// Kernel 3 (MFMA): out = tanh(base + relu(m @ W_d1) @ W_d2)
// (verified round 12; A-frags now loaded directly from fp16 m)
// ---------------------------------------------------------------------------
__global__ __launch_bounds__(256) void dense_tanh(
    const half8* __restrict__ mh,       // [N_NODES][8] fp16
    const float* __restrict__ W1,       // [64][64]
    const float* __restrict__ W2,       // [64][64]
    const float* __restrict__ base,
    float* __restrict__ out)
{
    __shared__ _Float16 tl[4][16][72];  // 9 KB: per-wave transpose tile
    int lane = threadIdx.x & 63;
    int w    = threadIdx.x >> 6;        // wave in block
    int wid  = (blockIdx.x * 256 + threadIdx.x) >> 6;
    if (wid >= MTILES) return;

    int mrow = lane & 15;
    int kb   = lane >> 4;
    int k0   = kb * 8;

    half8 b1[2][4], b2[2][4];
#pragma unroll
    for (int s = 0; s < 2; ++s)
#pragma unroll
        for (int n = 0; n < 4; ++n)
#pragma unroll
            for (int j = 0; j < 8; ++j) {
                b1[s][n][j] = (_Float16)W1[(s * 32 + k0 + j) * 64 + n * 16 + mrow];
                b2[s][n][j] = (_Float16)W2[(s * 32 + k0 + j) * 64 + n * 16 + mrow];
            }

    int row = wid * 16 + mrow;
    // A-frags: direct half8 loads ((s*32+k0) is a multiple of 8)
    half8 a[2];
#pragma unroll
    for (int s = 0; s < 2; ++s)
        a[s] = mh[(size_t)row * 8 + ((s * 32 + k0) >> 3)];

    f32x4 acc1[4];
#pragma unroll
    for (int n = 0; n < 4; ++n) acc1[n] = (f32x4)0.f;
#pragma unroll
    for (int s = 0; s < 2; ++s)
#pragma unroll
        for (int n = 0; n < 4; ++n)
            acc1[n] = __builtin_amdgcn_mfma_f32_16x16x32_f16(a[s], b1[s][n], acc1[n], 0, 0, 0);

#pragma unroll
    for (int n = 0; n < 4; ++n)
#pragma unroll
        for (int j = 0; j < 4; ++j)
            tl[w][kb * 4 + j][n * 16 + mrow] = (_Float16)fmaxf(acc1[n][j], 0.f);

    half8 a2[2];
#pragma unroll
    for (int s = 0; s < 2; ++s)
        a2[s] = *reinterpret_cast<const half8*>(&tl[w][mrow][s * 32 + k0]);

    f32x4 acc2[4];
#pragma unroll
    for (int n = 0; n < 4; ++n) acc2[n] = (f32x4)0.f;
#pragma unroll
    for (int s = 0; s < 2; ++s)
#pragma unroll
        for (int n = 0; n < 4; ++n)
            acc2[n] = __builtin_amdgcn_mfma_f32_16x16x32_f16(a2[s], b2[s][n], acc2[n], 0, 0, 0);

#pragma unroll
    for (int n = 0; n < 4; ++n)
#pragma unroll
        for (int j = 0; j < 4; ++j) {
            int r = wid * 16 + kb * 4 + j;
            int c = n * 16 + mrow;
            out[(size_t)r * 64 + c] = tanhf(base[(size_t)r * 64 + c] + acc2[n][j]);
        }
}

// ---------------------------------------------------------------------------
extern "C" void kernel_launch(void* const* d_in, const int* in_sizes, int n_in,
                              void* d_out, int out_size, void* d_ws, size_t ws_size,
                              hipStream_t stream)
{
    const float* feature = (const float*)d_in[0];
    const int*   src     = (const int*)d_in[1];
    const int*   dst     = (const int*)d_in[2];
    const float* W_lin   = (const float*)d_in[3];
    const float* W_d1    = (const float*)d_in[4];
    const float* W_d2    = (const float*)d_in[5];
    float* out = (float*)d_out;

    const size_t NODE_F = (size_t)N_NODES * OUT_DIM;   // 6.4M elems

    float*    base     = (float*)d_ws;                          // 25.6 MB
    _Float16* u1h      = (_Float16*)(base + NODE_F);            // 12.8 MB
    _Float16* mh       = u1h + NODE_F;                          // 12.8 MB
    int*      H        = (int*)(mh + NODE_F);                   // 3.2 MB
    int*      Btot     = H + ((size_t)NBUCKETS * NBINBLK + 4);  // NBUCKETS
    int*      node_off = Btot + (NBUCKETS + 4);                 // N_NODES+1
    int*      ebuf     = node_off + (N_NODES + 4);              // 3.2M ints

    // iter 1 collapses: u0 == 0 -> m == 0 -> h == 0 -> u1 = tanh(feature@W_lin)
    fused_gemm_hist<<<NBINBLK + GEMM_BLOCKS, 256, 0, stream>>>(
        feature, W_lin, base, u1h, dst, H);

    scan_local<<<NBUCKETS, NBINBLK, 0, stream>>>(H, Btot);
    bin_scatter<<<NBINBLK, 512, 0, stream>>>(src, dst, H, Btot, ebuf);
    bucket_sort<<<NBUCKETS, 512, 0, stream>>>(Btot, ebuf, node_off);

    int gather_blocks = (int)(((size_t)N_NODES * 64 + 255) / 256);   // 25000
    node_gather<<<gather_blocks, 256, 0, stream>>>(
        node_off, ebuf, (const half8*)u1h, (half8*)mh);

    dense_tanh<<<GEMM_BLOCKS, 256, 0, stream>>>(
        (const half8*)mh, W_d1, W_d2, base, out);
}

// Round 18
// 140.514 us; speedup vs baseline: 1.4247x; 1.1203x over previous
//
#include <hip/hip_runtime.h>
#include <math.h>

#define N_NODES 100000
#define N_EDGES 3200000
#define IN_DIM  128
#define OUT_DIM 64

#define BSHIFT   7
#define BNODES   128                                   // nodes per bucket
#define NBUCKETS ((N_NODES + BNODES - 1) / BNODES)     // 782
#define NBINBLK  1024
#define CHUNK    (N_EDGES / NBINBLK)                   // 3125 (exact)
#define SEGCAP   6144                                  // max edges/bucket (mean 4096, +32 sigma)
#define MTILES   (N_NODES / 16)                        // 6250 (exact)
#define GEMM_BLOCKS ((MTILES + 3) / 4)                 // 1563
#define RSTAGE   (SEGCAP / 512)                        // 12 regs/thread

typedef _Float16 half8 __attribute__((ext_vector_type(8)));
typedef float    f32x4 __attribute__((ext_vector_type(4)));

// XCD-aware swizzle (verified round 11): 128 consecutive logical blocks per
// XCD -> bucket-major ebuf segments write-combine in one L2.
__device__ __forceinline__ int xcd_swz(int i) {
    return (i & 7) * (NBINBLK / 8) + (i >> 3);   // bijective: 1024 = 8*128
}

// Exclusive scan of Btot[0..NBUCKETS) into LDS bs[] (512 threads).
// Integer Hillis-Steele -- bit-identical offsets (verified round 17).
__device__ __forceinline__ void scan_btot(
    const int* __restrict__ Btot, int* bs, int* tmp)
{
    int t = threadIdx.x;
    const int C = (NBUCKETS + 511) / 512;   // 2
    int b0 = t * C;
    int s = 0;
#pragma unroll
    for (int i = 0; i < C; ++i) {
        int idx = b0 + i;
        int v = (idx < NBUCKETS) ? Btot[idx] : 0;
        if (idx < NBUCKETS) bs[idx] = v;
        s += v;
    }
    tmp[t] = s;
    __syncthreads();
#pragma unroll
    for (int o = 1; o < 512; o <<= 1) {
        int v = (t >= o) ? tmp[t - o] : 0;
        __syncthreads();
        tmp[t] += v;
        __syncthreads();
    }
    int excl = (t == 0) ? 0 : tmp[t - 1];
#pragma unroll
    for (int i = 0; i < C; ++i) {
        int idx = b0 + i;
        if (idx < NBUCKETS) { int v = bs[idx]; bs[idx] = excl; excl += v; }
    }
    __syncthreads();
}

// ---------------------------------------------------------------------------
// Fused kernel: blocks [0,NBINBLK) run bin_hist; blocks [NBINBLK, +GEMM)
// run the MFMA gemm.  (verified round 15)
// ---------------------------------------------------------------------------
__global__ __launch_bounds__(256) void fused_gemm_hist(
    const float* __restrict__ feature,
    const float* __restrict__ Wlin,     // [128][64] row-major fp32
    float* __restrict__ base,
    _Float16* __restrict__ u1h,
    const int* __restrict__ dst,
    int* __restrict__ H)
{
    __shared__ int h[NBUCKETS];

    if (blockIdx.x < NBINBLK) {
        // ---- bin_hist path (verified round 12) ----
        for (int k = threadIdx.x; k < NBUCKETS; k += 256) h[k] = 0;
        __syncthreads();

        int b = xcd_swz(blockIdx.x);
        int beg = b * CHUNK, end = beg + CHUNK;
        for (int i = beg + threadIdx.x; i < end; i += 256)
            atomicAdd(&h[dst[i] >> BSHIFT], 1);
        __syncthreads();

        for (int k = threadIdx.x; k < NBUCKETS; k += 256)
            H[(size_t)k * NBINBLK + b] = h[k];
        return;
    }

    // ---- gemm path (verified rounds 9-12) ----
    int lane = threadIdx.x & 63;
    int wid  = ((blockIdx.x - NBINBLK) * 256 + threadIdx.x) >> 6;
    if (wid >= MTILES) return;

    int mrow = lane & 15;       // A row / B col / C col
    int kb   = lane >> 4;       // k-block 0..3
    int k0   = kb * 8;

    half8 b[4][4];
#pragma unroll
    for (int s = 0; s < 4; ++s)
#pragma unroll
        for (int n = 0; n < 4; ++n)
#pragma unroll
            for (int j = 0; j < 8; ++j)
                b[s][n][j] = (_Float16)Wlin[(s * 32 + k0 + j) * OUT_DIM + n * 16 + mrow];

    int row = wid * 16 + mrow;
    const float4* fr = reinterpret_cast<const float4*>(feature + (size_t)row * IN_DIM);
    half8 a[4];
#pragma unroll
    for (int s = 0; s < 4; ++s) {
        float4 lo = fr[(s * 32 + k0) >> 2];
        float4 hi = fr[((s * 32 + k0) >> 2) + 1];
        a[s][0] = (_Float16)lo.x; a[s][1] = (_Float16)lo.y;
        a[s][2] = (_Float16)lo.z; a[s][3] = (_Float16)lo.w;
        a[s][4] = (_Float16)hi.x; a[s][5] = (_Float16)hi.y;
        a[s][6] = (_Float16)hi.z; a[s][7] = (_Float16)hi.w;
    }

    f32x4 acc[4];
#pragma unroll
    for (int n = 0; n < 4; ++n) acc[n] = (f32x4)0.f;

#pragma unroll
    for (int s = 0; s < 4; ++s)
#pragma unroll
        for (int n = 0; n < 4; ++n)
            acc[n] = __builtin_amdgcn_mfma_f32_16x16x32_f16(a[s], b[s][n], acc[n], 0, 0, 0);

#pragma unroll
    for (int n = 0; n < 4; ++n)
#pragma unroll
        for (int j = 0; j < 4; ++j) {
            int r = wid * 16 + kb * 4 + j;
            int c = n * 16 + mrow;
            float v = acc[n][j];
            base[(size_t)r * OUT_DIM + c] = v;
            u1h[(size_t)r * OUT_DIM + c] = (_Float16)tanhf(v);
        }
}

// ---------------------------------------------------------------------------
// scan_local: per-bucket exclusive scan of H row; Btot[k] = inclusive total.
// (verified round 12)
// ---------------------------------------------------------------------------
__global__ __launch_bounds__(NBINBLK) void scan_local(
    int* __restrict__ H, int* __restrict__ Btot)
{
    __shared__ int s[NBINBLK];
    int k = blockIdx.x, t = threadIdx.x;
    int v = H[(size_t)k * NBINBLK + t];
    s[t] = v;
    __syncthreads();
#pragma unroll
    for (int off = 1; off < NBINBLK; off <<= 1) {
        int x = (t >= off) ? s[t - off] : 0;
        __syncthreads();
        s[t] += x;
        __syncthreads();
    }
    H[(size_t)k * NBINBLK + t] = s[t] - v;      // exclusive (local, no base)
    if (t == NBINBLK - 1) Btot[k] = s[t];       // inclusive total
}

// ---------------------------------------------------------------------------
// bin_scatter: derives bucket bases from raw Btot in-prologue.
// (verified rounds 16-17)
// ---------------------------------------------------------------------------
__global__ __launch_bounds__(512) void bin_scatter(
    const int* __restrict__ src,
    const int* __restrict__ dst,
    const int* __restrict__ H,
    const int* __restrict__ Btot,
    int* __restrict__ ebuf)
{
    __shared__ int cur[NBUCKETS];
    __shared__ int bs[NBUCKETS];
    __shared__ int tmp[512];

    scan_btot(Btot, bs, tmp);

    int b = xcd_swz(blockIdx.x);
    for (int k = threadIdx.x; k < NBUCKETS; k += 512)
        cur[k] = H[(size_t)k * NBINBLK + b] + bs[k];
    __syncthreads();

    int beg = b * CHUNK, end = beg + CHUNK;
    for (int i = beg + threadIdx.x; i < end; i += 512) {
        int d = dst[i];
        int k = d >> BSHIFT;
        int p = atomicAdd(&cur[k], 1);
        // pack: src (17 bits) | dlocal (7 bits) << 17
        ebuf[p] = src[i] | ((d & (BNODES - 1)) << 17);
    }
}

// ---------------------------------------------------------------------------
// sort_gather (round 18): fuses bucket_sort + node_gather.  Block k:
//  1. stage bucket edges into REGISTERS (12/thread, static indexing),
//     LDS-histogram by local node.
//  2. offsets -> st[]; scatter from regs into LDS seg (counting sort).
//  3. gather straight from seg: 64 groups x 8 lanes; group owns nodes
//     g, g+64; per edge each lane loads one half8 of the u1 row (4-deep
//     unroll); m row written once.  No CSR write-back, no node_off, no
//     global csr re-read (saves ~25.6 MB HBM + one dispatch).
// ---------------------------------------------------------------------------
__global__ __launch_bounds__(512) void sort_gather(
    const int* __restrict__ Btot,
    const int* __restrict__ ebuf,
    const half8* __restrict__ u1v,      // [N_NODES][8] fp16
    half8* __restrict__ mh)             // [N_NODES][8] fp16
{
    __shared__ int seg[SEGCAP];
    __shared__ int cnt[BNODES];
    __shared__ int off[BNODES];
    __shared__ int st[BNODES + 1];
    __shared__ int bs[NBUCKETS];
    __shared__ int tmp[512];

    scan_btot(Btot, bs, tmp);

    int k = blockIdx.x;
    int beg = bs[k];
    int end = (k + 1 < NBUCKETS) ? bs[k + 1] : N_EDGES;
    int n = end - beg;

    for (int j = threadIdx.x; j < BNODES; j += 512) cnt[j] = 0;
    __syncthreads();

    // 1. stage to registers + histogram (static r[] indexing -- rule #20)
    int r[RSTAGE];
#pragma unroll
    for (int it = 0; it < RSTAGE; ++it) {
        int i = threadIdx.x + it * 512;
        int v = (i < n) ? ebuf[beg + i] : -1;
        r[it] = v;
        if (v >= 0) atomicAdd(&cnt[v >> 17], 1);
    }
    __syncthreads();

    // 2. per-node offsets within bucket
    if (threadIdx.x == 0) {
        int excl = 0;
        for (int j = 0; j < BNODES; ++j) {
            st[j] = excl; off[j] = excl; excl += cnt[j];
        }
        st[BNODES] = excl;              // == n
    }
    __syncthreads();

    // counting-sort scatter regs -> LDS seg
#pragma unroll
    for (int it = 0; it < RSTAGE; ++it) {
        int v = r[it];
        if (v >= 0) {
            int p = atomicAdd(&off[v >> 17], 1);
            seg[p] = v & 0x1FFFF;
        }
    }
    __syncthreads();

    // 3. gather: group g (8 lanes) handles local nodes g, g+64
    int g = threadIdx.x >> 3;           // 0..63
    int c = threadIdx.x & 7;            // half8 column chunk
    int node0 = k * BNODES;

#pragma unroll
    for (int half = 0; half < 2; ++half) {
        int j = g + half * 64;
        int node = node0 + j;
        if (node >= N_NODES) break;
        int eb = st[j], ee = st[j + 1];

        float acc[8];
#pragma unroll
        for (int i = 0; i < 8; ++i) acc[i] = 0.f;

        int e = eb;
        for (; e + 4 <= ee; e += 4) {
            int s0 = seg[e];            // LDS broadcast across the 8 lanes
            int s1 = seg[e + 1];
            int s2 = seg[e + 2];
            int s3 = seg[e + 3];
            half8 a = u1v[(size_t)s0 * 8 + c];
            half8 b = u1v[(size_t)s1 * 8 + c];
            half8 gg = u1v[(size_t)s2 * 8 + c];
            half8 d = u1v[(size_t)s3 * 8 + c];
#pragma unroll
            for (int i = 0; i < 8; ++i)
                acc[i] += ((float)a[i] + (float)b[i]) + ((float)gg[i] + (float)d[i]);
        }
        for (; e < ee; ++e) {
            half8 a = u1v[(size_t)seg[e] * 8 + c];
#pragma unroll
            for (int i = 0; i < 8; ++i) acc[i] += (float)a[i];
        }

        half8 hv;
#pragma unroll
        for (int i = 0; i < 8; ++i) hv[i] = (_Float16)acc[i];
        mh[(size_t)node * 8 + c] = hv;  // 8 lanes x 16 B = 128 B row
    }
}

// ---------------------------------------------------------------------------
// Kernel 3 (MFMA): out = tanh(base + relu(m @ W_d1) @ W_d2)
// (verified rounds 12/17)
// ---------------------------------------------------------------------------
__global__ __launch_bounds__(256) void dense_tanh(
    const half8* __restrict__ mh,       // [N_NODES][8] fp16
    const float* __restrict__ W1,       // [64][64]
    const float* __restrict__ W2,       // [64][64]
    const float* __restrict__ base,
    float* __restrict__ out)
{
    __shared__ _Float16 tl[4][16][72];  // 9 KB: per-wave transpose tile
    int lane = threadIdx.x & 63;
    int w    = threadIdx.x >> 6;        // wave in block
    int wid  = (blockIdx.x * 256 + threadIdx.x) >> 6;
    if (wid >= MTILES) return;

    int mrow = lane & 15;
    int kb   = lane >> 4;
    int k0   = kb * 8;

    half8 b1[2][4], b2[2][4];
#pragma unroll
    for (int s = 0; s < 2; ++s)
#pragma unroll
        for (int n = 0; n < 4; ++n)
#pragma unroll
            for (int j = 0; j < 8; ++j) {
                b1[s][n][j] = (_Float16)W1[(s * 32 + k0 + j) * 64 + n * 16 + mrow];
                b2[s][n][j] = (_Float16)W2[(s * 32 + k0 + j) * 64 + n * 16 + mrow];
            }

    int row = wid * 16 + mrow;
    half8 a[2];
#pragma unroll
    for (int s = 0; s < 2; ++s)
        a[s] = mh[(size_t)row * 8 + ((s * 32 + k0) >> 3)];

    f32x4 acc1[4];
#pragma unroll
    for (int n = 0; n < 4; ++n) acc1[n] = (f32x4)0.f;
#pragma unroll
    for (int s = 0; s < 2; ++s)
#pragma unroll
        for (int n = 0; n < 4; ++n)
            acc1[n] = __builtin_amdgcn_mfma_f32_16x16x32_f16(a[s], b1[s][n], acc1[n], 0, 0, 0);

#pragma unroll
    for (int n = 0; n < 4; ++n)
#pragma unroll
        for (int j = 0; j < 4; ++j)
            tl[w][kb * 4 + j][n * 16 + mrow] = (_Float16)fmaxf(acc1[n][j], 0.f);

    half8 a2[2];
#pragma unroll
    for (int s = 0; s < 2; ++s)
        a2[s] = *reinterpret_cast<const half8*>(&tl[w][mrow][s * 32 + k0]);

    f32x4 acc2[4];
#pragma unroll
    for (int n = 0; n < 4; ++n) acc2[n] = (f32x4)0.f;
#pragma unroll
    for (int s = 0; s < 2; ++s)
#pragma unroll
        for (int n = 0; n < 4; ++n)
            acc2[n] = __builtin_amdgcn_mfma_f32_16x16x32_f16(a2[s], b2[s][n], acc2[n], 0, 0, 0);

#pragma unroll
    for (int n = 0; n < 4; ++n)
#pragma unroll
        for (int j = 0; j < 4; ++j) {
            int r = wid * 16 + kb * 4 + j;
            int c = n * 16 + mrow;
            out[(size_t)r * 64 + c] = tanhf(base[(size_t)r * 64 + c] + acc2[n][j]);
        }
}

// ---------------------------------------------------------------------------
extern "C" void kernel_launch(void* const* d_in, const int* in_sizes, int n_in,
                              void* d_out, int out_size, void* d_ws, size_t ws_size,
                              hipStream_t stream)
{
    const float* feature = (const float*)d_in[0];
    const int*   src     = (const int*)d_in[1];
    const int*   dst     = (const int*)d_in[2];
    const float* W_lin   = (const float*)d_in[3];
    const float* W_d1    = (const float*)d_in[4];
    const float* W_d2    = (const float*)d_in[5];
    float* out = (float*)d_out;

    const size_t NODE_F = (size_t)N_NODES * OUT_DIM;   // 6.4M elems

    float*    base     = (float*)d_ws;                          // 25.6 MB
    _Float16* u1h      = (_Float16*)(base + NODE_F);            // 12.8 MB
    _Float16* mh       = u1h + NODE_F;                          // 12.8 MB
    int*      H        = (int*)(mh + NODE_F);                   // 3.2 MB
    int*      Btot     = H + ((size_t)NBUCKETS * NBINBLK + 4);  // NBUCKETS
    int*      ebuf     = Btot + (NBUCKETS + 4);                 // 3.2M ints

    // iter 1 collapses: u0 == 0 -> m == 0 -> h == 0 -> u1 = tanh(feature@W_lin)
    fused_gemm_hist<<<NBINBLK + GEMM_BLOCKS, 256, 0, stream>>>(
        feature, W_lin, base, u1h, dst, H);

    scan_local<<<NBUCKETS, NBINBLK, 0, stream>>>(H, Btot);
    bin_scatter<<<NBINBLK, 512, 0, stream>>>(src, dst, H, Btot, ebuf);
    sort_gather<<<NBUCKETS, 512, 0, stream>>>(
        Btot, ebuf, (const half8*)u1h, (half8*)mh);

    dense_tanh<<<GEMM_BLOCKS, 256, 0, stream>>>(
        (const half8*)mh, W_d1, W_d2, base, out);
}